// Round 5
// baseline (700.124 us; speedup 1.0000x reference)
//
#include <hip/hip_runtime.h>
#include <stdint.h>
#include <math.h>

#define D 128

// bf16 pack/unpack (RNE)
__device__ __forceinline__ unsigned f2bf_pk(float a, float b) {
    union { float f; unsigned u; } x, y; x.f = a; y.f = b;
    unsigned ra = x.u + 0x7FFF + ((x.u >> 16) & 1);
    unsigned rb = y.u + 0x7FFF + ((y.u >> 16) & 1);
    return (ra >> 16) | (rb & 0xFFFF0000u);
}
__device__ __forceinline__ float2 bf2f2(unsigned u) {
    union { unsigned u; float f; } lo, hi;
    lo.u = u << 16; hi.u = u & 0xFFFF0000u;
    return make_float2(lo.f, hi.f);
}

// ---- Stage A: degree / dinv / CSR build ----

__global__ void k_degree(const int* __restrict__ dst, int E, int* __restrict__ degi) {
    int i = blockIdx.x * blockDim.x + threadIdx.x;
    if (i < E) atomicAdd(&degi[dst[i]], 1);
}

__global__ void k_dinv(const int* __restrict__ degi, float* __restrict__ dinv, int N) {
    int i = blockIdx.x * blockDim.x + threadIdx.x;
    if (i < N) dinv[i] = rsqrtf((float)degi[i] + 1.0f);
}

// ---- 3-phase parallel exclusive scan: degi[0..N) -> rowstart[0..N] ----

__global__ __launch_bounds__(256) void k_scan_bsum(const int* __restrict__ degi, int* __restrict__ bsum, int N) {
    __shared__ int ws[4];
    int i = blockIdx.x * 256 + threadIdx.x;
    int v = (i < N) ? degi[i] : 0;
#pragma unroll
    for (int off = 1; off < 64; off <<= 1) v += __shfl_xor(v, off, 64);
    if ((threadIdx.x & 63) == 0) ws[threadIdx.x >> 6] = v;
    __syncthreads();
    if (threadIdx.x == 0) bsum[blockIdx.x] = ws[0] + ws[1] + ws[2] + ws[3];
}

__global__ __launch_bounds__(1024) void k_scan_boff(const int* __restrict__ bsum, int* __restrict__ boff,
                                                    int nb, int* __restrict__ rowstart, int N, int E) {
    __shared__ int s[1024];
    int t = threadIdx.x;
    s[t] = (t < nb) ? bsum[t] : 0;
    __syncthreads();
    for (int off = 1; off < 1024; off <<= 1) {
        int v = (t >= off) ? s[t - off] : 0;
        __syncthreads();
        s[t] += v;
        __syncthreads();
    }
    if (t < nb) boff[t] = (t == 0) ? 0 : s[t - 1];
    if (t == 0) rowstart[N] = E;
}

__global__ __launch_bounds__(256) void k_scan_final(const int* __restrict__ degi, const int* __restrict__ boff,
                                                    int* __restrict__ rowstart, int N) {
    __shared__ int s[256];
    int t = threadIdx.x;
    int i = blockIdx.x * 256 + t;
    s[t] = (i < N) ? degi[i] : 0;
    __syncthreads();
    for (int off = 1; off < 256; off <<= 1) {
        int v = (t >= off) ? s[t - off] : 0;
        __syncthreads();
        s[t] += v;
        __syncthreads();
    }
    if (i < N) rowstart[i] = boff[blockIdx.x] + ((t == 0) ? 0 : s[t - 1]);
}

__global__ void k_scatter(const int* __restrict__ src, const int* __restrict__ dst, int E,
                          const int* __restrict__ rowstart, int* __restrict__ cursor,
                          int* __restrict__ col, int* __restrict__ eid) {
    int i = blockIdx.x * blockDim.x + threadIdx.x;
    if (i < E) {
        int d = dst[i];
        int pos = rowstart[d] + atomicAdd(&cursor[d], 1);
        col[pos] = src[i];
        eid[pos] = i;
    }
}

// ---- layer-1 transform  g1 = bf16(dinv * (x @ W1)),  x:[N,8] f32 ----

__global__ __launch_bounds__(256) void k_xform1(const float* __restrict__ x, const float* __restrict__ W1,
                                                const float* __restrict__ dinv, unsigned* __restrict__ g, int N) {
    __shared__ float Ws[8 * D];
    int t = threadIdx.x;
    for (int i = t; i < 8 * D; i += 256) Ws[i] = W1[i];
    __syncthreads();
    int node = blockIdx.x * 4 + (t >> 6);
    int l = t & 63;
    if (node < N) {
        float s0 = 0.f, s1 = 0.f;
#pragma unroll
        for (int k = 0; k < 8; ++k) {
            float xv = x[node * 8 + k];
            s0 += xv * Ws[k * D + 2 * l];
            s1 += xv * Ws[k * D + 2 * l + 1];
        }
        float di = dinv[node];
        g[node * 64 + l] = f2bf_pk(s0 * di, s1 * di);
    }
}

// ---- Aggregation: wave/node; 4 neighbors/batch x 16 lanes; 2-deep pipelined gathers ----

__global__ __launch_bounds__(256) void k_agg(const uint4* __restrict__ g, const int* __restrict__ rowstart,
                                             const int* __restrict__ col, const float* __restrict__ dinv,
                                             const float* __restrict__ bias, float* __restrict__ h, int N) {
    int wave = (blockIdx.x * blockDim.x + threadIdx.x) >> 6;
    int lane = threadIdx.x & 63;
    if (wave >= N) return;
    int i = wave;
    int sub = lane >> 4;
    int r = lane & 15;
    float acc[8];
#pragma unroll
    for (int j = 0; j < 8; ++j) acc[j] = 0.f;
    int lo = rowstart[i], hi = rowstart[i + 1];

    int idx0 = lo + sub;
    bool v0 = idx0 < hi;
    int s0 = v0 ? col[idx0] : 0;
    int idx1 = idx0 + 4;
    bool v1 = idx1 < hi;
    int s1 = v1 ? col[idx1] : 0;
    uint4 av0 = make_uint4(0, 0, 0, 0);
    if (v0) av0 = g[s0 * 16 + r];

    for (int base = lo; base < hi; base += 4) {
        int idx2 = idx1 + 4;
        bool v2 = idx2 < hi;
        int s2 = v2 ? col[idx2] : 0;       // col prefetch, 2 batches ahead
        uint4 av1;
        if (v1) av1 = g[s1 * 16 + r];      // gather prefetch, 1 batch ahead
        if (v0) {
            float2 p;
            p = bf2f2(av0.x); acc[0] += p.x; acc[1] += p.y;
            p = bf2f2(av0.y); acc[2] += p.x; acc[3] += p.y;
            p = bf2f2(av0.z); acc[4] += p.x; acc[5] += p.y;
            p = bf2f2(av0.w); acc[6] += p.x; acc[7] += p.y;
        }
        av0 = av1; v0 = v1; s1 = s2; v1 = v2; idx1 = idx2;
    }
#pragma unroll
    for (int j = 0; j < 8; ++j) {
        acc[j] += __shfl_xor(acc[j], 16, 64);
        acc[j] += __shfl_xor(acc[j], 32, 64);
    }
    if (sub == 0) {
        uint4 sv = g[i * 16 + r];   // self term
        float2 p;
        p = bf2f2(sv.x); acc[0] += p.x; acc[1] += p.y;
        p = bf2f2(sv.y); acc[2] += p.x; acc[3] += p.y;
        p = bf2f2(sv.z); acc[4] += p.x; acc[5] += p.y;
        p = bf2f2(sv.w); acc[6] += p.x; acc[7] += p.y;
        float di = dinv[i];
        float4 b0 = ((const float4*)bias)[r * 2];
        float4 b1 = ((const float4*)bias)[r * 2 + 1];
        float4 o0, o1;
        o0.x = fmaxf(acc[0] * di + b0.x, 0.f);
        o0.y = fmaxf(acc[1] * di + b0.y, 0.f);
        o0.z = fmaxf(acc[2] * di + b0.z, 0.f);
        o0.w = fmaxf(acc[3] * di + b0.w, 0.f);
        o1.x = fmaxf(acc[4] * di + b1.x, 0.f);
        o1.y = fmaxf(acc[5] * di + b1.y, 0.f);
        o1.z = fmaxf(acc[6] * di + b1.z, 0.f);
        o1.w = fmaxf(acc[7] * di + b1.w, 0.f);
        float4* hp = (float4*)(h + (size_t)i * D + r * 8);
        hp[0] = o0; hp[1] = o1;
    }
}

// ---- Node GEMM, conflict-free LDS: rows {g,g+16,g+32,g+48}, hs LD=132, Ws in 2 k-phases ----

#define GEMM_NPB 64
#define HS_LD 132
__global__ __launch_bounds__(256) void k_gemm128(const float* __restrict__ W, const float* __restrict__ in,
                                                 const float* __restrict__ bias, const float* __restrict__ dinv,
                                                 unsigned* __restrict__ out, int N) {
    __shared__ float Ws[64 * 64];            // 16 KB, one k-phase at a time
    __shared__ float hs[GEMM_NPB * HS_LD];   // 33 KB, padded rows (bank shift 4/row)
    int t = threadIdx.x;
    int fbase = (blockIdx.x & 1) << 6;
    int base = (blockIdx.x >> 1) * GEMM_NPB;
    for (int i = t; i < GEMM_NPB * D; i += 256) {
        int node = base + (i >> 7);
        hs[(i >> 7) * HS_LD + (i & 127)] = (node < N) ? in[node * D + (i & 127)] : 0.f;
    }
    int g = t >> 4;           // row group: rows g + 16j
    int tf = (t & 15) << 2;   // f-quad
    float acc[4][4];
#pragma unroll
    for (int a = 0; a < 4; ++a)
#pragma unroll
        for (int b = 0; b < 4; ++b) acc[a][b] = 0.f;
    for (int kp = 0; kp < 2; ++kp) {
        __syncthreads();      // hs staged (kp=0) / Ws phase-0 reads done (kp=1)
        for (int i = t; i < 64 * 64; i += 256) {
            int k = i >> 6, fl = i & 63;
            Ws[i] = W[((kp * 64 + k) << 7) + fbase + fl];
        }
        __syncthreads();
        for (int k2 = 0; k2 < 64; k2 += 4) {
            float4 w[4];
            float4 hv[4];
#pragma unroll
            for (int kk = 0; kk < 4; ++kk) w[kk] = *(const float4*)&Ws[(k2 + kk) * 64 + tf];
#pragma unroll
            for (int j = 0; j < 4; ++j) hv[j] = *(const float4*)&hs[(g + 16 * j) * HS_LD + kp * 64 + k2];
#pragma unroll
            for (int j = 0; j < 4; ++j) {
                float hk0 = hv[j].x, hk1 = hv[j].y, hk2 = hv[j].z, hk3 = hv[j].w;
                acc[j][0] += hk0 * w[0].x + hk1 * w[1].x + hk2 * w[2].x + hk3 * w[3].x;
                acc[j][1] += hk0 * w[0].y + hk1 * w[1].y + hk2 * w[2].y + hk3 * w[3].y;
                acc[j][2] += hk0 * w[0].z + hk1 * w[1].z + hk2 * w[2].z + hk3 * w[3].z;
                acc[j][3] += hk0 * w[0].w + hk1 * w[1].w + hk2 * w[2].w + hk3 * w[3].w;
            }
        }
    }
    float bv0 = 0.f, bv1 = 0.f, bv2 = 0.f, bv3 = 0.f;
    if (bias) {
        bv0 = bias[fbase + tf + 0];
        bv1 = bias[fbase + tf + 1];
        bv2 = bias[fbase + tf + 2];
        bv3 = bias[fbase + tf + 3];
    }
#pragma unroll
    for (int j = 0; j < 4; ++j) {
        int node = base + g + 16 * j;
        if (node >= N) continue;
        float sc = dinv ? dinv[node] : 1.0f;
        float o0 = acc[j][0] * sc + bv0;
        float o1 = acc[j][1] * sc + bv1;
        float o2 = acc[j][2] * sc + bv2;
        float o3 = acc[j][3] * sc + bv3;
        ((uint2*)out)[node * 32 + ((fbase + tf) >> 2)] = make_uint2(f2bf_pk(o0, o1), f2bf_pk(o2, o3));
    }
}

// ---- Edge output, CSR-ordered, 2-deep pipelined: wave/dst; 4 edges/batch x 16 lanes ----

__global__ __launch_bounds__(256) void k_edge(const uint4* __restrict__ a, const uint4* __restrict__ c,
                                              const int* __restrict__ rowstart, const int* __restrict__ col,
                                              const int* __restrict__ eid,
                                              const float* __restrict__ Wfin, const float* __restrict__ bfin,
                                              float* __restrict__ out, int N) {
    int wave = (blockIdx.x * blockDim.x + threadIdx.x) >> 6;
    int lane = threadIdx.x & 63;
    if (wave >= N) return;
    int d = wave;
    int g = lane >> 4;
    int r = lane & 15;

    float wf0[8], wf1[8];
    const float4* wv = (const float4*)Wfin;
#pragma unroll
    for (int q = 0; q < 4; ++q) {
        float4 m = wv[r * 4 + q];
        wf0[2 * q] = m.x; wf1[2 * q] = m.y;
        wf0[2 * q + 1] = m.z; wf1[2 * q + 1] = m.w;
    }
    float bf0 = bfin[0], bf1 = bfin[1];

    float cf[8];
    {
        uint4 cv = c[d * 16 + r];
        float2 p;
        p = bf2f2(cv.x); cf[0] = p.x; cf[1] = p.y;
        p = bf2f2(cv.y); cf[2] = p.x; cf[3] = p.y;
        p = bf2f2(cv.z); cf[4] = p.x; cf[5] = p.y;
        p = bf2f2(cv.w); cf[6] = p.x; cf[7] = p.y;
    }

    int lo = rowstart[d], hi = rowstart[d + 1];
    int idx0 = lo + g;
    bool v0 = idx0 < hi;
    int s0 = v0 ? col[idx0] : 0;
    int idx1 = idx0 + 4;
    bool v1 = idx1 < hi;
    int s1 = v1 ? col[idx1] : 0;
    uint4 av0 = make_uint4(0, 0, 0, 0);
    if (v0) av0 = a[s0 * 16 + r];

    for (int base = lo; base < hi; base += 4) {
        int idx2 = idx1 + 4;
        bool v2 = idx2 < hi;
        int s2 = v2 ? col[idx2] : 0;   // col prefetch, 2 ahead
        uint4 av1;
        if (v1) av1 = a[s1 * 16 + r];  // gather prefetch, 1 ahead
        float p0 = 0.f, p1 = 0.f;
        float2 p;
        float z;
        p = bf2f2(av0.x);
        z = fmaxf(p.x + cf[0], 0.f); p0 += z * wf0[0]; p1 += z * wf1[0];
        z = fmaxf(p.y + cf[1], 0.f); p0 += z * wf0[1]; p1 += z * wf1[1];
        p = bf2f2(av0.y);
        z = fmaxf(p.x + cf[2], 0.f); p0 += z * wf0[2]; p1 += z * wf1[2];
        z = fmaxf(p.y + cf[3], 0.f); p0 += z * wf0[3]; p1 += z * wf1[3];
        p = bf2f2(av0.z);
        z = fmaxf(p.x + cf[4], 0.f); p0 += z * wf0[4]; p1 += z * wf1[4];
        z = fmaxf(p.y + cf[5], 0.f); p0 += z * wf0[5]; p1 += z * wf1[5];
        p = bf2f2(av0.w);
        z = fmaxf(p.x + cf[6], 0.f); p0 += z * wf0[6]; p1 += z * wf1[6];
        z = fmaxf(p.y + cf[7], 0.f); p0 += z * wf0[7]; p1 += z * wf1[7];
        p0 += __shfl_xor(p0, 1, 64);
        p0 += __shfl_xor(p0, 2, 64);
        p0 += __shfl_xor(p0, 4, 64);
        p0 += __shfl_xor(p0, 8, 64);
        p1 += __shfl_xor(p1, 1, 64);
        p1 += __shfl_xor(p1, 2, 64);
        p1 += __shfl_xor(p1, 4, 64);
        p1 += __shfl_xor(p1, 8, 64);
        if (r == 0 && v0) {
            int e = eid[base + g];
            float l0 = p0 + bf0, l1 = p1 + bf1;
            float m = fmaxf(l0, l1);
            float lse = m + logf(expf(l0 - m) + expf(l1 - m));
            *((float2*)(out + 2 * (size_t)e)) = make_float2(l0 - lse, l1 - lse);
        }
        av0 = av1; v0 = v1; s1 = s2; v1 = v2; idx1 = idx2;
    }
}

extern "C" void kernel_launch(void* const* d_in, const int* in_sizes, int n_in,
                              void* d_out, int out_size, void* d_ws, size_t ws_size,
                              hipStream_t stream) {
    const float* x     = (const float*)d_in[0];
    const int*   ei    = (const int*)d_in[1];
    const float* W1    = (const float*)d_in[2];
    const float* b1    = (const float*)d_in[3];
    const float* W2    = (const float*)d_in[4];
    const float* b2    = (const float*)d_in[5];
    const float* Wlin1 = (const float*)d_in[6];
    const float* blin1 = (const float*)d_in[7];
    const float* Wfin  = (const float*)d_in[8];
    const float* bfin  = (const float*)d_in[9];
    float* out = (float*)d_out;

    int N = in_sizes[0] / 8;
    int E = in_sizes[1] / 2;
    const int* src = ei;
    const int* dst = ei + E;
    int nb = (N + 255) / 256;

    char* w = (char*)d_ws;
    int* degi = (int*)w;      w += (size_t)N * 4;
    int* cursor = (int*)w;    w += (size_t)N * 4;
    int* rowstart = (int*)w;  w += (size_t)(N + 1) * 4;
    int* col = (int*)w;       w += (size_t)E * 4;
    int* eid = (int*)w;       w += (size_t)E * 4;
    float* dinv = (float*)w;  w += (size_t)N * 4;
    int* bsum = (int*)w;      w += (size_t)nb * 4;
    int* boff = (int*)w;      w += (size_t)nb * 4;
    w = (char*)(((uintptr_t)w + 255) & ~(uintptr_t)255);
    unsigned* bufG = (unsigned*)w; w += (size_t)N * 64 * 4;   // bf16-packed g1/g2
    float*    bufH = (float*)w;    w += (size_t)N * D * 4;    // fp32 h1/h2
    unsigned* bufA = (unsigned*)w; w += (size_t)N * 64 * 4;   // bf16-packed a
    unsigned* bufC = (unsigned*)w; w += (size_t)N * 64 * 4;   // bf16-packed c

    hipMemsetAsync(degi, 0, (size_t)N * 8, stream);   // degi + cursor contiguous

    k_degree<<<(E + 255) / 256, 256, 0, stream>>>(dst, E, degi);
    k_dinv<<<(N + 255) / 256, 256, 0, stream>>>(degi, dinv, N);
    k_scan_bsum<<<nb, 256, 0, stream>>>(degi, bsum, N);
    k_scan_boff<<<1, 1024, 0, stream>>>(bsum, boff, nb, rowstart, N, E);
    k_scan_final<<<nb, 256, 0, stream>>>(degi, boff, rowstart, N);
    k_scatter<<<(E + 255) / 256, 256, 0, stream>>>(src, dst, E, rowstart, cursor, col, eid);

    // layer 1
    k_xform1<<<(N + 3) / 4, 256, 0, stream>>>(x, W1, dinv, bufG, N);
    k_agg<<<(N + 3) / 4, 256, 0, stream>>>((const uint4*)bufG, rowstart, col, dinv, b1, bufH, N);

    // layer 2
    int gblocks = ((N + GEMM_NPB - 1) / GEMM_NPB) * 2;
    k_gemm128<<<gblocks, 256, 0, stream>>>(W2, bufH, nullptr, dinv, bufG, N);
    k_agg<<<(N + 3) / 4, 256, 0, stream>>>((const uint4*)bufG, rowstart, col, dinv, b2, bufH, N);

    // edge MLP factorization: a = h2@Wtop ; c = h2@Wbot + blin1
    k_gemm128<<<gblocks, 256, 0, stream>>>(Wlin1, bufH, nullptr, nullptr, bufA, N);
    k_gemm128<<<gblocks, 256, 0, stream>>>(Wlin1 + D * D, bufH, blin1, nullptr, bufC, N);

    k_edge<<<(N + 3) / 4, 256, 0, stream>>>((const uint4*)bufA, (const uint4*)bufC,
                                            rowstart, col, eid, Wfin, bfin, out, N);
}

// Round 6
// 362.211 us; speedup vs baseline: 1.9329x; 1.9329x over previous
//
#include <hip/hip_runtime.h>
#include <stdint.h>
#include <math.h>

#define D 128

typedef unsigned short u16;
typedef __attribute__((ext_vector_type(8))) short bf16x8;
typedef __attribute__((ext_vector_type(4))) float f32x4;

union BU { uint4 u; bf16x8 s; };

// bf16 pack/unpack (RNE)
__device__ __forceinline__ unsigned f2bf_pk(float a, float b) {
    union { float f; unsigned u; } x, y; x.f = a; y.f = b;
    unsigned ra = x.u + 0x7FFF + ((x.u >> 16) & 1);
    unsigned rb = y.u + 0x7FFF + ((y.u >> 16) & 1);
    return (ra >> 16) | (rb & 0xFFFF0000u);
}
__device__ __forceinline__ u16 f2bf(float f) {
    union { float f; unsigned u; } x; x.f = f;
    unsigned r = x.u + 0x7FFF + ((x.u >> 16) & 1);
    return (u16)(r >> 16);
}
__device__ __forceinline__ float2 bf2f2(unsigned u) {
    union { unsigned u; float f; } lo, hi;
    lo.u = u << 16; hi.u = u & 0xFFFF0000u;
    return make_float2(lo.f, hi.f);
}

// ---- Stage A: degree / dinv / CSR build ----

__global__ void k_degree(const int* __restrict__ dst, int E, int* __restrict__ degi) {
    int i = blockIdx.x * blockDim.x + threadIdx.x;
    if (i < E) atomicAdd(&degi[dst[i]], 1);
}

__global__ void k_dinv(const int* __restrict__ degi, float* __restrict__ dinv, int N) {
    int i = blockIdx.x * blockDim.x + threadIdx.x;
    if (i < N) dinv[i] = rsqrtf((float)degi[i] + 1.0f);
}

// ---- 3-phase parallel exclusive scan: degi[0..N) -> rowstart[0..N] ----

__global__ __launch_bounds__(256) void k_scan_bsum(const int* __restrict__ degi, int* __restrict__ bsum, int N) {
    __shared__ int ws[4];
    int i = blockIdx.x * 256 + threadIdx.x;
    int v = (i < N) ? degi[i] : 0;
#pragma unroll
    for (int off = 1; off < 64; off <<= 1) v += __shfl_xor(v, off, 64);
    if ((threadIdx.x & 63) == 0) ws[threadIdx.x >> 6] = v;
    __syncthreads();
    if (threadIdx.x == 0) bsum[blockIdx.x] = ws[0] + ws[1] + ws[2] + ws[3];
}

__global__ __launch_bounds__(1024) void k_scan_boff(const int* __restrict__ bsum, int* __restrict__ boff,
                                                    int nb, int* __restrict__ rowstart, int N, int E) {
    __shared__ int s[1024];
    int t = threadIdx.x;
    s[t] = (t < nb) ? bsum[t] : 0;
    __syncthreads();
    for (int off = 1; off < 1024; off <<= 1) {
        int v = (t >= off) ? s[t - off] : 0;
        __syncthreads();
        s[t] += v;
        __syncthreads();
    }
    if (t < nb) boff[t] = (t == 0) ? 0 : s[t - 1];
    if (t == 0) rowstart[N] = E;
}

__global__ __launch_bounds__(256) void k_scan_final(const int* __restrict__ degi, const int* __restrict__ boff,
                                                    int* __restrict__ rowstart, int N) {
    __shared__ int s[256];
    int t = threadIdx.x;
    int i = blockIdx.x * 256 + t;
    s[t] = (i < N) ? degi[i] : 0;
    __syncthreads();
    for (int off = 1; off < 256; off <<= 1) {
        int v = (t >= off) ? s[t - off] : 0;
        __syncthreads();
        s[t] += v;
        __syncthreads();
    }
    if (i < N) rowstart[i] = boff[blockIdx.x] + ((t == 0) ? 0 : s[t - 1]);
}

__global__ void k_scatter(const int* __restrict__ src, const int* __restrict__ dst, int E,
                          const int* __restrict__ rowstart, int* __restrict__ cursor,
                          int* __restrict__ col, int* __restrict__ eid) {
    int i = blockIdx.x * blockDim.x + threadIdx.x;
    if (i < E) {
        int d = dst[i];
        int pos = rowstart[d] + atomicAdd(&cursor[d], 1);
        col[pos] = src[i];
        eid[pos] = i;
    }
}

// ---- Weight prep: fp32 W[128][128] -> bf16 swizzled MFMA-B layout  ----
// wswz[kc][ct][lane][j] = W[kc*32 + (lane>>4)*8 + j][ct*16 + (lane&15)]
// one u32 (j-pair) per thread; 3 matrices: W2, Wlin-top, Wlin-bot

__global__ __launch_bounds__(256) void k_wprep(const float* __restrict__ W2, const float* __restrict__ Wlin,
                                               unsigned* __restrict__ wswz) {
    int tid = blockIdx.x * 256 + threadIdx.x;
    if (tid >= 3 * 8192) return;
    int m = tid >> 13;
    int r = tid & 8191;
    int jp = r & 3;
    int lane = (r >> 2) & 63;
    int ct = (r >> 8) & 7;
    int kc = r >> 11;
    int k0 = kc * 32 + (lane >> 4) * 8 + 2 * jp;
    int n = ct * 16 + (lane & 15);
    const float* src = (m == 0) ? W2 : (Wlin + (m - 1) * 16384);
    wswz[tid] = f2bf_pk(src[k0 * 128 + n], src[(k0 + 1) * 128 + n]);
}

// ---- layer-1 transform  g1 = bf16(dinv * (x @ W1)),  x:[N,8] f32 ----

__global__ __launch_bounds__(256) void k_xform1(const float* __restrict__ x, const float* __restrict__ W1,
                                                const float* __restrict__ dinv, unsigned* __restrict__ g, int N) {
    __shared__ float Ws[8 * D];
    int t = threadIdx.x;
    for (int i = t; i < 8 * D; i += 256) Ws[i] = W1[i];
    __syncthreads();
    int node = blockIdx.x * 4 + (t >> 6);
    int l = t & 63;
    if (node < N) {
        float s0 = 0.f, s1 = 0.f;
#pragma unroll
        for (int k = 0; k < 8; ++k) {
            float xv = x[node * 8 + k];
            s0 += xv * Ws[k * D + 2 * l];
            s1 += xv * Ws[k * D + 2 * l + 1];
        }
        float di = dinv[node];
        g[node * 64 + l] = f2bf_pk(s0 * di, s1 * di);
    }
}

// ---- Aggregation: wave/node; 4 neighbors/batch x 16 lanes; 2-deep pipeline; bf16 h out ----

__global__ __launch_bounds__(256) void k_agg(const uint4* __restrict__ g, const int* __restrict__ rowstart,
                                             const int* __restrict__ col, const float* __restrict__ dinv,
                                             const float* __restrict__ bias, uint4* __restrict__ h, int N) {
    int wave = (blockIdx.x * blockDim.x + threadIdx.x) >> 6;
    int lane = threadIdx.x & 63;
    if (wave >= N) return;
    int i = wave;
    int sub = lane >> 4;
    int r = lane & 15;
    float acc[8];
#pragma unroll
    for (int j = 0; j < 8; ++j) acc[j] = 0.f;
    int lo = rowstart[i], hi = rowstart[i + 1];

    int idx0 = lo + sub;
    bool v0 = idx0 < hi;
    int s0 = v0 ? col[idx0] : 0;
    int idx1 = idx0 + 4;
    bool v1 = idx1 < hi;
    int s1 = v1 ? col[idx1] : 0;
    uint4 av0 = make_uint4(0, 0, 0, 0);
    if (v0) av0 = g[s0 * 16 + r];

    for (int base = lo; base < hi; base += 4) {
        int idx2 = idx1 + 4;
        bool v2 = idx2 < hi;
        int s2 = v2 ? col[idx2] : 0;
        uint4 av1;
        if (v1) av1 = g[s1 * 16 + r];
        if (v0) {
            float2 p;
            p = bf2f2(av0.x); acc[0] += p.x; acc[1] += p.y;
            p = bf2f2(av0.y); acc[2] += p.x; acc[3] += p.y;
            p = bf2f2(av0.z); acc[4] += p.x; acc[5] += p.y;
            p = bf2f2(av0.w); acc[6] += p.x; acc[7] += p.y;
        }
        av0 = av1; v0 = v1; s1 = s2; v1 = v2; idx1 = idx2;
    }
#pragma unroll
    for (int j = 0; j < 8; ++j) {
        acc[j] += __shfl_xor(acc[j], 16, 64);
        acc[j] += __shfl_xor(acc[j], 32, 64);
    }
    if (sub == 0) {
        uint4 sv = g[i * 16 + r];   // self term
        float2 p;
        p = bf2f2(sv.x); acc[0] += p.x; acc[1] += p.y;
        p = bf2f2(sv.y); acc[2] += p.x; acc[3] += p.y;
        p = bf2f2(sv.z); acc[4] += p.x; acc[5] += p.y;
        p = bf2f2(sv.w); acc[6] += p.x; acc[7] += p.y;
        float di = dinv[i];
        float4 b0 = ((const float4*)bias)[r * 2];
        float4 b1 = ((const float4*)bias)[r * 2 + 1];
        float r0 = fmaxf(acc[0] * di + b0.x, 0.f);
        float r1 = fmaxf(acc[1] * di + b0.y, 0.f);
        float r2 = fmaxf(acc[2] * di + b0.z, 0.f);
        float r3 = fmaxf(acc[3] * di + b0.w, 0.f);
        float r4 = fmaxf(acc[4] * di + b1.x, 0.f);
        float r5 = fmaxf(acc[5] * di + b1.y, 0.f);
        float r6 = fmaxf(acc[6] * di + b1.z, 0.f);
        float r7 = fmaxf(acc[7] * di + b1.w, 0.f);
        uint4 o;
        o.x = f2bf_pk(r0, r1);
        o.y = f2bf_pk(r2, r3);
        o.z = f2bf_pk(r4, r5);
        o.w = f2bf_pk(r6, r7);
        h[i * 16 + r] = o;
    }
}

// ---- MFMA node GEMM: out_bf16[n][128] = pack((h_bf16[n,:] @ W) * dinv? + bias?) ----
// block: 4 waves x 16 nodes; wave: 16 nodes x 128 cols, K=128 in 4 chunks of 32.
// A straight from global (1 dwordx4/lane/chunk, coalesced); B from pre-swizzled global (L2-hot).

__global__ __launch_bounds__(256) void k_gemm_mfma(const uint4* __restrict__ wswz, const uint4* __restrict__ in,
                                                   const float* __restrict__ bias, const float* __restrict__ dinv,
                                                   u16* __restrict__ out, int N) {
    int t = threadIdx.x;
    int wv = t >> 6;
    int lane = t & 63;
    int quad = lane >> 4;
    int l15 = lane & 15;
    int nbase = blockIdx.x * 64 + wv * 16;

    f32x4 acc[8];
#pragma unroll
    for (int ct = 0; ct < 8; ++ct) acc[ct] = (f32x4){0.f, 0.f, 0.f, 0.f};

    int arow = nbase + l15;
    const uint4* arowp = in + (size_t)(arow < N ? arow : 0) * 16;

#pragma unroll
    for (int kc = 0; kc < 4; ++kc) {
        BU a; a.u = arowp[kc * 4 + quad];
#pragma unroll
        for (int ct = 0; ct < 8; ++ct) {
            BU b; b.u = wswz[(kc * 8 + ct) * 64 + lane];
            acc[ct] = __builtin_amdgcn_mfma_f32_16x16x32_bf16(a.s, b.s, acc[ct], 0, 0, 0);
        }
    }
#pragma unroll
    for (int reg = 0; reg < 4; ++reg) {
        int node = nbase + quad * 4 + reg;
        if (node >= N) continue;
        float sc = dinv ? dinv[node] : 1.0f;
#pragma unroll
        for (int ct = 0; ct < 8; ++ct) {
            int colj = ct * 16 + l15;
            float v = acc[ct][reg] * sc + (bias ? bias[colj] : 0.f);
            out[(size_t)node * 128 + colj] = f2bf(v);
        }
    }
}

// ---- Edge output, CSR-ordered, 2-deep pipelined: wave/dst; 4 edges/batch x 16 lanes ----

__global__ __launch_bounds__(256) void k_edge(const uint4* __restrict__ a, const uint4* __restrict__ c,
                                              const int* __restrict__ rowstart, const int* __restrict__ col,
                                              const int* __restrict__ eid,
                                              const float* __restrict__ Wfin, const float* __restrict__ bfin,
                                              float* __restrict__ out, int N) {
    int wave = (blockIdx.x * blockDim.x + threadIdx.x) >> 6;
    int lane = threadIdx.x & 63;
    if (wave >= N) return;
    int d = wave;
    int g = lane >> 4;
    int r = lane & 15;

    float wf0[8], wf1[8];
    const float4* wvp = (const float4*)Wfin;
#pragma unroll
    for (int q = 0; q < 4; ++q) {
        float4 m = wvp[r * 4 + q];
        wf0[2 * q] = m.x; wf1[2 * q] = m.y;
        wf0[2 * q + 1] = m.z; wf1[2 * q + 1] = m.w;
    }
    float bf0 = bfin[0], bf1 = bfin[1];

    float cf[8];
    {
        uint4 cv = c[d * 16 + r];
        float2 p;
        p = bf2f2(cv.x); cf[0] = p.x; cf[1] = p.y;
        p = bf2f2(cv.y); cf[2] = p.x; cf[3] = p.y;
        p = bf2f2(cv.z); cf[4] = p.x; cf[5] = p.y;
        p = bf2f2(cv.w); cf[6] = p.x; cf[7] = p.y;
    }

    int lo = rowstart[d], hi = rowstart[d + 1];
    int idx0 = lo + g;
    bool v0 = idx0 < hi;
    int s0 = v0 ? col[idx0] : 0;
    int idx1 = idx0 + 4;
    bool v1 = idx1 < hi;
    int s1 = v1 ? col[idx1] : 0;
    uint4 av0 = make_uint4(0, 0, 0, 0);
    if (v0) av0 = a[s0 * 16 + r];

    for (int base = lo; base < hi; base += 4) {
        int idx2 = idx1 + 4;
        bool v2 = idx2 < hi;
        int s2 = v2 ? col[idx2] : 0;
        uint4 av1;
        if (v1) av1 = a[s1 * 16 + r];
        float p0 = 0.f, p1 = 0.f;
        float2 p;
        float z;
        p = bf2f2(av0.x);
        z = fmaxf(p.x + cf[0], 0.f); p0 += z * wf0[0]; p1 += z * wf1[0];
        z = fmaxf(p.y + cf[1], 0.f); p0 += z * wf0[1]; p1 += z * wf1[1];
        p = bf2f2(av0.y);
        z = fmaxf(p.x + cf[2], 0.f); p0 += z * wf0[2]; p1 += z * wf1[2];
        z = fmaxf(p.y + cf[3], 0.f); p0 += z * wf0[3]; p1 += z * wf1[3];
        p = bf2f2(av0.z);
        z = fmaxf(p.x + cf[4], 0.f); p0 += z * wf0[4]; p1 += z * wf1[4];
        z = fmaxf(p.y + cf[5], 0.f); p0 += z * wf0[5]; p1 += z * wf1[5];
        p = bf2f2(av0.w);
        z = fmaxf(p.x + cf[6], 0.f); p0 += z * wf0[6]; p1 += z * wf1[6];
        z = fmaxf(p.y + cf[7], 0.f); p0 += z * wf0[7]; p1 += z * wf1[7];
        p0 += __shfl_xor(p0, 1, 64);
        p0 += __shfl_xor(p0, 2, 64);
        p0 += __shfl_xor(p0, 4, 64);
        p0 += __shfl_xor(p0, 8, 64);
        p1 += __shfl_xor(p1, 1, 64);
        p1 += __shfl_xor(p1, 2, 64);
        p1 += __shfl_xor(p1, 4, 64);
        p1 += __shfl_xor(p1, 8, 64);
        if (r == 0 && v0) {
            int e = eid[base + g];
            float l0 = p0 + bf0, l1 = p1 + bf1;
            float m = fmaxf(l0, l1);
            float lse = m + logf(expf(l0 - m) + expf(l1 - m));
            *((float2*)(out + 2 * (size_t)e)) = make_float2(l0 - lse, l1 - lse);
        }
        av0 = av1; v0 = v1; s1 = s2; v1 = v2; idx1 = idx2;
    }
}

extern "C" void kernel_launch(void* const* d_in, const int* in_sizes, int n_in,
                              void* d_out, int out_size, void* d_ws, size_t ws_size,
                              hipStream_t stream) {
    const float* x     = (const float*)d_in[0];
    const int*   ei    = (const int*)d_in[1];
    const float* W1    = (const float*)d_in[2];
    const float* b1    = (const float*)d_in[3];
    const float* W2    = (const float*)d_in[4];
    const float* b2    = (const float*)d_in[5];
    const float* Wlin1 = (const float*)d_in[6];
    const float* blin1 = (const float*)d_in[7];
    const float* Wfin  = (const float*)d_in[8];
    const float* bfin  = (const float*)d_in[9];
    float* out = (float*)d_out;

    int N = in_sizes[0] / 8;
    int E = in_sizes[1] / 2;
    const int* src = ei;
    const int* dst = ei + E;
    int nb = (N + 255) / 256;

    char* w = (char*)d_ws;
    int* degi = (int*)w;      w += (size_t)N * 4;
    int* cursor = (int*)w;    w += (size_t)N * 4;
    int* rowstart = (int*)w;  w += (size_t)(N + 1) * 4;
    int* col = (int*)w;       w += (size_t)E * 4;
    int* eid = (int*)w;       w += (size_t)E * 4;
    float* dinv = (float*)w;  w += (size_t)N * 4;
    int* bsum = (int*)w;      w += (size_t)nb * 4;
    int* boff = (int*)w;      w += (size_t)nb * 4;
    w = (char*)(((uintptr_t)w + 255) & ~(uintptr_t)255);
    unsigned* wswz = (unsigned*)w; w += (size_t)3 * 8192 * 4;   // bf16-swizzled W2 / Wlin-top / Wlin-bot
    unsigned* bufG = (unsigned*)w; w += (size_t)N * 64 * 4;     // bf16-packed g1/g2
    unsigned* bufH = (unsigned*)w; w += (size_t)N * 64 * 4;     // bf16-packed h1/h2
    unsigned* bufA = (unsigned*)w; w += (size_t)N * 64 * 4;     // bf16-packed a
    unsigned* bufC = (unsigned*)w; w += (size_t)N * 64 * 4;     // bf16-packed c

    hipMemsetAsync(degi, 0, (size_t)N * 8, stream);   // degi + cursor contiguous

    k_wprep<<<96, 256, 0, stream>>>(W2, Wlin1, wswz);
    k_degree<<<(E + 255) / 256, 256, 0, stream>>>(dst, E, degi);
    k_dinv<<<(N + 255) / 256, 256, 0, stream>>>(degi, dinv, N);
    k_scan_bsum<<<nb, 256, 0, stream>>>(degi, bsum, N);
    k_scan_boff<<<1, 1024, 0, stream>>>(bsum, boff, nb, rowstart, N, E);
    k_scan_final<<<nb, 256, 0, stream>>>(degi, boff, rowstart, N);
    k_scatter<<<(E + 255) / 256, 256, 0, stream>>>(src, dst, E, rowstart, cursor, col, eid);

    // layer 1
    k_xform1<<<(N + 3) / 4, 256, 0, stream>>>(x, W1, dinv, bufG, N);
    k_agg<<<(N + 3) / 4, 256, 0, stream>>>((const uint4*)bufG, rowstart, col, dinv, b1, (uint4*)bufH, N);

    // layer 2: g2 = dinv*(h1@W2)
    int mblocks = (N + 63) / 64;
    k_gemm_mfma<<<mblocks, 256, 0, stream>>>((const uint4*)wswz, (const uint4*)bufH,
                                             nullptr, dinv, (u16*)bufG, N);
    k_agg<<<(N + 3) / 4, 256, 0, stream>>>((const uint4*)bufG, rowstart, col, dinv, b2, (uint4*)bufH, N);

    // edge MLP factorization: a = h2@Wtop ; c = h2@Wbot + blin1
    k_gemm_mfma<<<mblocks, 256, 0, stream>>>((const uint4*)(wswz + 8192), (const uint4*)bufH,
                                             nullptr, nullptr, (u16*)bufA, N);
    k_gemm_mfma<<<mblocks, 256, 0, stream>>>((const uint4*)(wswz + 16384), (const uint4*)bufH,
                                             blin1, nullptr, (u16*)bufC, N);

    k_edge<<<(N + 3) / 4, 256, 0, stream>>>((const uint4*)bufA, (const uint4*)bufC,
                                            rowstart, col, eid, Wfin, bfin, out, N);
}

// Round 7
// 330.242 us; speedup vs baseline: 2.1200x; 1.0968x over previous
//
#include <hip/hip_runtime.h>
#include <stdint.h>
#include <math.h>

#define D 128

typedef unsigned short u16;
typedef __attribute__((ext_vector_type(8))) short bf16x8;
typedef __attribute__((ext_vector_type(4))) float f32x4;

union BU { uint4 u; bf16x8 s; };

// bf16 pack/unpack (RNE)
__device__ __forceinline__ unsigned f2bf_pk(float a, float b) {
    union { float f; unsigned u; } x, y; x.f = a; y.f = b;
    unsigned ra = x.u + 0x7FFF + ((x.u >> 16) & 1);
    unsigned rb = y.u + 0x7FFF + ((y.u >> 16) & 1);
    return (ra >> 16) | (rb & 0xFFFF0000u);
}
__device__ __forceinline__ u16 f2bf(float f) {
    union { float f; unsigned u; } x; x.f = f;
    unsigned r = x.u + 0x7FFF + ((x.u >> 16) & 1);
    return (u16)(r >> 16);
}
__device__ __forceinline__ float2 bf2f2(unsigned u) {
    union { unsigned u; float f; } lo, hi;
    lo.u = u << 16; hi.u = u & 0xFFFF0000u;
    return make_float2(lo.f, hi.f);
}

// ---- Stage A: CSR build with 8-way privatized histograms ----

__global__ __launch_bounds__(256) void k_degree8(const int* __restrict__ dst, int E,
                                                 int* __restrict__ hist8, int N) {
    int i = blockIdx.x * 256 + threadIdx.x;
    int copy = blockIdx.x & 7;
    if (i < E) atomicAdd(&hist8[copy * N + dst[i]], 1);
}

// per node: total degree, dinv, and convert hist8 copies to per-copy exclusive offsets
__global__ __launch_bounds__(256) void k_xcdoff(int* __restrict__ hist8, int* __restrict__ degi,
                                                float* __restrict__ dinv, int N) {
    int i = blockIdx.x * 256 + threadIdx.x;
    if (i >= N) return;
    int run = 0;
#pragma unroll
    for (int j = 0; j < 8; ++j) {
        int c = hist8[j * N + i];
        hist8[j * N + i] = run;
        run += c;
    }
    degi[i] = run;
    dinv[i] = rsqrtf((float)run + 1.0f);
}

// ---- 3-phase parallel exclusive scan: degi[0..N) -> rowstart[0..N] ----

__global__ __launch_bounds__(256) void k_scan_bsum(const int* __restrict__ degi, int* __restrict__ bsum, int N) {
    __shared__ int ws[4];
    int i = blockIdx.x * 256 + threadIdx.x;
    int v = (i < N) ? degi[i] : 0;
#pragma unroll
    for (int off = 1; off < 64; off <<= 1) v += __shfl_xor(v, off, 64);
    if ((threadIdx.x & 63) == 0) ws[threadIdx.x >> 6] = v;
    __syncthreads();
    if (threadIdx.x == 0) bsum[blockIdx.x] = ws[0] + ws[1] + ws[2] + ws[3];
}

__global__ __launch_bounds__(1024) void k_scan_boff(const int* __restrict__ bsum, int* __restrict__ boff,
                                                    int nb, int* __restrict__ rowstart, int N, int E) {
    __shared__ int s[1024];
    int t = threadIdx.x;
    s[t] = (t < nb) ? bsum[t] : 0;
    __syncthreads();
    for (int off = 1; off < 1024; off <<= 1) {
        int v = (t >= off) ? s[t - off] : 0;
        __syncthreads();
        s[t] += v;
        __syncthreads();
    }
    if (t < nb) boff[t] = (t == 0) ? 0 : s[t - 1];
    if (t == 0) rowstart[N] = E;
}

__global__ __launch_bounds__(256) void k_scan_final(const int* __restrict__ degi, const int* __restrict__ boff,
                                                    int* __restrict__ rowstart, int N) {
    __shared__ int s[256];
    int t = threadIdx.x;
    int i = blockIdx.x * 256 + t;
    s[t] = (i < N) ? degi[i] : 0;
    __syncthreads();
    for (int off = 1; off < 256; off <<= 1) {
        int v = (t >= off) ? s[t - off] : 0;
        __syncthreads();
        s[t] += v;
        __syncthreads();
    }
    if (i < N) rowstart[i] = boff[blockIdx.x] + ((t == 0) ? 0 : s[t - 1]);
}

// scatter with privatized cursors (hist8 now holds per-copy base offsets; atomicAdd = cursor)
__global__ __launch_bounds__(256) void k_scatter8(const int* __restrict__ src, const int* __restrict__ dst, int E,
                                                  const int* __restrict__ rowstart, int* __restrict__ hist8,
                                                  int2* __restrict__ coleid, int N) {
    int i = blockIdx.x * 256 + threadIdx.x;
    int copy = blockIdx.x & 7;
    if (i < E) {
        int d = dst[i];
        int off = atomicAdd(&hist8[copy * N + d], 1);
        coleid[rowstart[d] + off] = make_int2(src[i], i);
    }
}

// ---- Weight prep: fp32 W[128][128] -> bf16 swizzled MFMA-B layout ----
// wswz[kc][ct][lane][j] = W[kc*32 + (lane>>4)*8 + j][ct*16 + (lane&15)]

__global__ __launch_bounds__(256) void k_wprep(const float* __restrict__ W2, const float* __restrict__ Wlin,
                                               unsigned* __restrict__ wswz) {
    int tid = blockIdx.x * 256 + threadIdx.x;
    if (tid >= 3 * 8192) return;
    int m = tid >> 13;
    int r = tid & 8191;
    int jp = r & 3;
    int lane = (r >> 2) & 63;
    int ct = (r >> 8) & 7;
    int kc = r >> 11;
    int k0 = kc * 32 + (lane >> 4) * 8 + 2 * jp;
    int n = ct * 16 + (lane & 15);
    const float* src = (m == 0) ? W2 : (Wlin + (m - 1) * 16384);
    wswz[tid] = f2bf_pk(src[k0 * 128 + n], src[(k0 + 1) * 128 + n]);
}

// ---- layer-1 transform  g1 = bf16(dinv * (x @ W1)),  x:[N,8] f32 ----

__global__ __launch_bounds__(256) void k_xform1(const float* __restrict__ x, const float* __restrict__ W1,
                                                const float* __restrict__ dinv, unsigned* __restrict__ g, int N) {
    __shared__ float Ws[8 * D];
    int t = threadIdx.x;
    for (int i = t; i < 8 * D; i += 256) Ws[i] = W1[i];
    __syncthreads();
    int node = blockIdx.x * 4 + (t >> 6);
    int l = t & 63;
    if (node < N) {
        float s0 = 0.f, s1 = 0.f;
#pragma unroll
        for (int k = 0; k < 8; ++k) {
            float xv = x[node * 8 + k];
            s0 += xv * Ws[k * D + 2 * l];
            s1 += xv * Ws[k * D + 2 * l + 1];
        }
        float di = dinv[node];
        g[node * 64 + l] = f2bf_pk(s0 * di, s1 * di);
    }
}

// ---- Aggregation: wave/node; 4 neighbors/batch x 16 lanes; 2-deep pipeline; bf16 h out ----

__global__ __launch_bounds__(256) void k_agg(const uint4* __restrict__ g, const int* __restrict__ rowstart,
                                             const int2* __restrict__ coleid, const float* __restrict__ dinv,
                                             const float* __restrict__ bias, uint4* __restrict__ h, int N) {
    int wave = (blockIdx.x * blockDim.x + threadIdx.x) >> 6;
    int lane = threadIdx.x & 63;
    if (wave >= N) return;
    int i = wave;
    int sub = lane >> 4;
    int r = lane & 15;
    float acc[8];
#pragma unroll
    for (int j = 0; j < 8; ++j) acc[j] = 0.f;
    int lo = rowstart[i], hi = rowstart[i + 1];

    int idx0 = lo + sub;
    bool v0 = idx0 < hi;
    int s0 = v0 ? coleid[idx0].x : 0;
    int idx1 = idx0 + 4;
    bool v1 = idx1 < hi;
    int s1 = v1 ? coleid[idx1].x : 0;
    uint4 av0 = make_uint4(0, 0, 0, 0);
    if (v0) av0 = g[s0 * 16 + r];

    for (int base = lo; base < hi; base += 4) {
        int idx2 = idx1 + 4;
        bool v2 = idx2 < hi;
        int s2 = v2 ? coleid[idx2].x : 0;
        uint4 av1;
        if (v1) av1 = g[s1 * 16 + r];
        if (v0) {
            float2 p;
            p = bf2f2(av0.x); acc[0] += p.x; acc[1] += p.y;
            p = bf2f2(av0.y); acc[2] += p.x; acc[3] += p.y;
            p = bf2f2(av0.z); acc[4] += p.x; acc[5] += p.y;
            p = bf2f2(av0.w); acc[6] += p.x; acc[7] += p.y;
        }
        av0 = av1; v0 = v1; s1 = s2; v1 = v2; idx1 = idx2;
    }
#pragma unroll
    for (int j = 0; j < 8; ++j) {
        acc[j] += __shfl_xor(acc[j], 16, 64);
        acc[j] += __shfl_xor(acc[j], 32, 64);
    }
    if (sub == 0) {
        uint4 sv = g[i * 16 + r];   // self term
        float2 p;
        p = bf2f2(sv.x); acc[0] += p.x; acc[1] += p.y;
        p = bf2f2(sv.y); acc[2] += p.x; acc[3] += p.y;
        p = bf2f2(sv.z); acc[4] += p.x; acc[5] += p.y;
        p = bf2f2(sv.w); acc[6] += p.x; acc[7] += p.y;
        float di = dinv[i];
        float4 b0 = ((const float4*)bias)[r * 2];
        float4 b1 = ((const float4*)bias)[r * 2 + 1];
        float r0 = fmaxf(acc[0] * di + b0.x, 0.f);
        float r1 = fmaxf(acc[1] * di + b0.y, 0.f);
        float r2 = fmaxf(acc[2] * di + b0.z, 0.f);
        float r3 = fmaxf(acc[3] * di + b0.w, 0.f);
        float r4 = fmaxf(acc[4] * di + b1.x, 0.f);
        float r5 = fmaxf(acc[5] * di + b1.y, 0.f);
        float r6 = fmaxf(acc[6] * di + b1.z, 0.f);
        float r7 = fmaxf(acc[7] * di + b1.w, 0.f);
        uint4 o;
        o.x = f2bf_pk(r0, r1);
        o.y = f2bf_pk(r2, r3);
        o.z = f2bf_pk(r4, r5);
        o.w = f2bf_pk(r6, r7);
        h[i * 16 + r] = o;
    }
}

// ---- MFMA node GEMM (single): out_bf16 = pack((h @ W) * dinv? + bias?) ----

__global__ __launch_bounds__(256) void k_gemm_mfma(const uint4* __restrict__ wswz, const uint4* __restrict__ in,
                                                   const float* __restrict__ bias, const float* __restrict__ dinv,
                                                   u16* __restrict__ out, int N) {
    int t = threadIdx.x;
    int wv = t >> 6;
    int lane = t & 63;
    int quad = lane >> 4;
    int l15 = lane & 15;
    int nbase = blockIdx.x * 64 + wv * 16;

    f32x4 acc[8];
#pragma unroll
    for (int ct = 0; ct < 8; ++ct) acc[ct] = (f32x4){0.f, 0.f, 0.f, 0.f};

    int arow = nbase + l15;
    const uint4* arowp = in + (size_t)(arow < N ? arow : 0) * 16;

#pragma unroll
    for (int kc = 0; kc < 4; ++kc) {
        BU a; a.u = arowp[kc * 4 + quad];
#pragma unroll
        for (int ct = 0; ct < 8; ++ct) {
            BU b; b.u = wswz[(kc * 8 + ct) * 64 + lane];
            acc[ct] = __builtin_amdgcn_mfma_f32_16x16x32_bf16(a.s, b.s, acc[ct], 0, 0, 0);
        }
    }
#pragma unroll
    for (int reg = 0; reg < 4; ++reg) {
        int node = nbase + quad * 4 + reg;
        if (node >= N) continue;
        float sc = dinv ? dinv[node] : 1.0f;
#pragma unroll
        for (int ct = 0; ct < 8; ++ct) {
            int colj = ct * 16 + l15;
            float v = acc[ct][reg] * sc + (bias ? bias[colj] : 0.f);
            out[(size_t)node * 128 + colj] = f2bf(v);
        }
    }
}

// ---- Fused dual MFMA GEMM: a = h@Wtop ; c = h@Wbot + blin (one pass over h) ----

__global__ __launch_bounds__(256) void k_gemm_dual(const uint4* __restrict__ wA, const uint4* __restrict__ wC,
                                                   const uint4* __restrict__ in, const float* __restrict__ biasC,
                                                   u16* __restrict__ outA, u16* __restrict__ outC, int N) {
    int t = threadIdx.x;
    int wv = t >> 6;
    int lane = t & 63;
    int quad = lane >> 4;
    int l15 = lane & 15;
    int nbase = blockIdx.x * 64 + wv * 16;

    f32x4 accA[8], accC[8];
#pragma unroll
    for (int ct = 0; ct < 8; ++ct) {
        accA[ct] = (f32x4){0.f, 0.f, 0.f, 0.f};
        accC[ct] = (f32x4){0.f, 0.f, 0.f, 0.f};
    }

    int arow = nbase + l15;
    const uint4* arowp = in + (size_t)(arow < N ? arow : 0) * 16;

#pragma unroll
    for (int kc = 0; kc < 4; ++kc) {
        BU a; a.u = arowp[kc * 4 + quad];
#pragma unroll
        for (int ct = 0; ct < 8; ++ct) {
            BU bA; bA.u = wA[(kc * 8 + ct) * 64 + lane];
            accA[ct] = __builtin_amdgcn_mfma_f32_16x16x32_bf16(a.s, bA.s, accA[ct], 0, 0, 0);
            BU bC; bC.u = wC[(kc * 8 + ct) * 64 + lane];
            accC[ct] = __builtin_amdgcn_mfma_f32_16x16x32_bf16(a.s, bC.s, accC[ct], 0, 0, 0);
        }
    }
#pragma unroll
    for (int reg = 0; reg < 4; ++reg) {
        int node = nbase + quad * 4 + reg;
        if (node >= N) continue;
#pragma unroll
        for (int ct = 0; ct < 8; ++ct) {
            int colj = ct * 16 + l15;
            outA[(size_t)node * 128 + colj] = f2bf(accA[ct][reg]);
            outC[(size_t)node * 128 + colj] = f2bf(accC[ct][reg] + biasC[colj]);
        }
    }
}

// ---- Edge output, CSR-ordered, 2-deep pipelined: wave/dst; 4 edges/batch x 16 lanes ----

__global__ __launch_bounds__(256) void k_edge(const uint4* __restrict__ a, const uint4* __restrict__ c,
                                              const int* __restrict__ rowstart, const int2* __restrict__ coleid,
                                              const float* __restrict__ Wfin, const float* __restrict__ bfin,
                                              float* __restrict__ out, int N) {
    int wave = (blockIdx.x * blockDim.x + threadIdx.x) >> 6;
    int lane = threadIdx.x & 63;
    if (wave >= N) return;
    int d = wave;
    int g = lane >> 4;
    int r = lane & 15;

    float wf0[8], wf1[8];
    const float4* wvp = (const float4*)Wfin;
#pragma unroll
    for (int q = 0; q < 4; ++q) {
        float4 m = wvp[r * 4 + q];
        wf0[2 * q] = m.x; wf1[2 * q] = m.y;
        wf0[2 * q + 1] = m.z; wf1[2 * q + 1] = m.w;
    }
    float bf0 = bfin[0], bf1 = bfin[1];

    float cf[8];
    {
        uint4 cv = c[d * 16 + r];
        float2 p;
        p = bf2f2(cv.x); cf[0] = p.x; cf[1] = p.y;
        p = bf2f2(cv.y); cf[2] = p.x; cf[3] = p.y;
        p = bf2f2(cv.z); cf[4] = p.x; cf[5] = p.y;
        p = bf2f2(cv.w); cf[6] = p.x; cf[7] = p.y;
    }

    int lo = rowstart[d], hi = rowstart[d + 1];
    int idx0 = lo + g;
    bool v0 = idx0 < hi;
    int2 ce0 = v0 ? coleid[idx0] : make_int2(0, 0);
    int idx1 = idx0 + 4;
    bool v1 = idx1 < hi;
    int2 ce1 = v1 ? coleid[idx1] : make_int2(0, 0);
    uint4 av0 = make_uint4(0, 0, 0, 0);
    if (v0) av0 = a[ce0.x * 16 + r];

    for (int base = lo; base < hi; base += 4) {
        int idx2 = idx1 + 4;
        bool v2 = idx2 < hi;
        int2 ce2 = v2 ? coleid[idx2] : make_int2(0, 0);
        uint4 av1;
        if (v1) av1 = a[ce1.x * 16 + r];
        float p0 = 0.f, p1 = 0.f;
        float2 p;
        float z;
        p = bf2f2(av0.x);
        z = fmaxf(p.x + cf[0], 0.f); p0 += z * wf0[0]; p1 += z * wf1[0];
        z = fmaxf(p.y + cf[1], 0.f); p0 += z * wf0[1]; p1 += z * wf1[1];
        p = bf2f2(av0.y);
        z = fmaxf(p.x + cf[2], 0.f); p0 += z * wf0[2]; p1 += z * wf1[2];
        z = fmaxf(p.y + cf[3], 0.f); p0 += z * wf0[3]; p1 += z * wf1[3];
        p = bf2f2(av0.z);
        z = fmaxf(p.x + cf[4], 0.f); p0 += z * wf0[4]; p1 += z * wf1[4];
        z = fmaxf(p.y + cf[5], 0.f); p0 += z * wf0[5]; p1 += z * wf1[5];
        p = bf2f2(av0.w);
        z = fmaxf(p.x + cf[6], 0.f); p0 += z * wf0[6]; p1 += z * wf1[6];
        z = fmaxf(p.y + cf[7], 0.f); p0 += z * wf0[7]; p1 += z * wf1[7];
        p0 += __shfl_xor(p0, 1, 64);
        p0 += __shfl_xor(p0, 2, 64);
        p0 += __shfl_xor(p0, 4, 64);
        p0 += __shfl_xor(p0, 8, 64);
        p1 += __shfl_xor(p1, 1, 64);
        p1 += __shfl_xor(p1, 2, 64);
        p1 += __shfl_xor(p1, 4, 64);
        p1 += __shfl_xor(p1, 8, 64);
        if (r == 0 && v0) {
            int e = ce0.y;
            float l0 = p0 + bf0, l1 = p1 + bf1;
            float m = fmaxf(l0, l1);
            float lse = m + logf(expf(l0 - m) + expf(l1 - m));
            *((float2*)(out + 2 * (size_t)e)) = make_float2(l0 - lse, l1 - lse);
        }
        av0 = av1; v0 = v1; ce0 = ce1; ce1 = ce2; v1 = v2; idx1 = idx2;
    }
}

extern "C" void kernel_launch(void* const* d_in, const int* in_sizes, int n_in,
                              void* d_out, int out_size, void* d_ws, size_t ws_size,
                              hipStream_t stream) {
    const float* x     = (const float*)d_in[0];
    const int*   ei    = (const int*)d_in[1];
    const float* W1    = (const float*)d_in[2];
    const float* b1    = (const float*)d_in[3];
    const float* W2    = (const float*)d_in[4];
    const float* b2    = (const float*)d_in[5];
    const float* Wlin1 = (const float*)d_in[6];
    const float* blin1 = (const float*)d_in[7];
    const float* Wfin  = (const float*)d_in[8];
    const float* bfin  = (const float*)d_in[9];
    float* out = (float*)d_out;

    int N = in_sizes[0] / 8;
    int E = in_sizes[1] / 2;
    const int* src = ei;
    const int* dst = ei + E;
    int nb = (N + 255) / 256;

    char* w = (char*)d_ws;
    int* hist8 = (int*)w;     w += (size_t)8 * N * 4;
    int* degi = (int*)w;      w += (size_t)N * 4;
    int* rowstart = (int*)w;  w += (size_t)(N + 1) * 4;
    float* dinv = (float*)w;  w += (size_t)N * 4;
    int* bsum = (int*)w;      w += (size_t)nb * 4;
    int* boff = (int*)w;      w += (size_t)nb * 4;
    w = (char*)(((uintptr_t)w + 255) & ~(uintptr_t)255);
    int2* coleid = (int2*)w;  w += (size_t)E * 8;
    unsigned* wswz = (unsigned*)w; w += (size_t)3 * 8192 * 4;   // bf16-swizzled W2 / Wlin-top / Wlin-bot
    unsigned* bufG = (unsigned*)w; w += (size_t)N * 64 * 4;     // bf16-packed g1/g2
    unsigned* bufH = (unsigned*)w; w += (size_t)N * 64 * 4;     // bf16-packed h1/h2
    unsigned* bufA = (unsigned*)w; w += (size_t)N * 64 * 4;     // bf16-packed a
    unsigned* bufC = (unsigned*)w; w += (size_t)N * 64 * 4;     // bf16-packed c

    hipMemsetAsync(hist8, 0, (size_t)8 * N * 4, stream);

    k_wprep<<<96, 256, 0, stream>>>(W2, Wlin1, wswz);
    int eb = (E + 255) / 256;
    k_degree8<<<eb, 256, 0, stream>>>(dst, E, hist8, N);
    k_xcdoff<<<nb, 256, 0, stream>>>(hist8, degi, dinv, N);
    k_scan_bsum<<<nb, 256, 0, stream>>>(degi, bsum, N);
    k_scan_boff<<<1, 1024, 0, stream>>>(bsum, boff, nb, rowstart, N, E);
    k_scan_final<<<nb, 256, 0, stream>>>(degi, boff, rowstart, N);
    k_scatter8<<<eb, 256, 0, stream>>>(src, dst, E, rowstart, hist8, coleid, N);

    // layer 1
    k_xform1<<<(N + 3) / 4, 256, 0, stream>>>(x, W1, dinv, bufG, N);
    k_agg<<<(N + 3) / 4, 256, 0, stream>>>((const uint4*)bufG, rowstart, coleid, dinv, b1, (uint4*)bufH, N);

    // layer 2: g2 = dinv*(h1@W2)
    int mblocks = (N + 63) / 64;
    k_gemm_mfma<<<mblocks, 256, 0, stream>>>((const uint4*)wswz, (const uint4*)bufH,
                                             nullptr, dinv, (u16*)bufG, N);
    k_agg<<<(N + 3) / 4, 256, 0, stream>>>((const uint4*)bufG, rowstart, coleid, dinv, b2, (uint4*)bufH, N);

    // edge MLP factorization: a = h2@Wtop ; c = h2@Wbot + blin1  (fused, one pass over h2)
    k_gemm_dual<<<mblocks, 256, 0, stream>>>((const uint4*)(wswz + 8192), (const uint4*)(wswz + 16384),
                                             (const uint4*)bufH, blin1, (u16*)bufA, (u16*)bufC, N);

    k_edge<<<(N + 3) / 4, 256, 0, stream>>>((const uint4*)bufA, (const uint4*)bufC,
                                            rowstart, coleid, Wfin, bfin, out, N);
}

// Round 9
// 321.489 us; speedup vs baseline: 2.1778x; 1.0272x over previous
//
#include <hip/hip_runtime.h>
#include <stdint.h>
#include <math.h>

#define D 128

typedef unsigned short u16;
typedef __attribute__((ext_vector_type(8))) short bf16x8;
typedef __attribute__((ext_vector_type(4))) float f32x4;

union BU { uint4 u; bf16x8 s; };

// bf16 pack/unpack (RNE)
__device__ __forceinline__ unsigned f2bf_pk(float a, float b) {
    union { float f; unsigned u; } x, y; x.f = a; y.f = b;
    unsigned ra = x.u + 0x7FFF + ((x.u >> 16) & 1);
    unsigned rb = y.u + 0x7FFF + ((y.u >> 16) & 1);
    return (ra >> 16) | (rb & 0xFFFF0000u);
}
__device__ __forceinline__ u16 f2bf(float f) {
    union { float f; unsigned u; } x; x.f = f;
    unsigned r = x.u + 0x7FFF + ((x.u >> 16) & 1);
    return (u16)(r >> 16);
}
__device__ __forceinline__ float2 bf2f2(unsigned u) {
    union { unsigned u; float f; } lo, hi;
    lo.u = u << 16; hi.u = u & 0xFFFF0000u;
    return make_float2(lo.f, hi.f);
}
__device__ __forceinline__ int padded8(int deg) {
    int pd = (deg + 7) & ~7;
    return pd ? pd : 8;
}

// ---- CSR build: 8-way privatized histogram, int4-vectorized ----
// copy index derived from int4-group index i: copy = (i>>8)&7 — MUST match k_scatter_fill.

__global__ __launch_bounds__(256) void k_degree8(const int* __restrict__ dst, int E,
                                                 int* __restrict__ hist8, int N) {
    int i = blockIdx.x * 256 + threadIdx.x;
    int copy = blockIdx.x & 7;
    int E4 = E >> 2;
    if (i < E4) {
        int4 d = ((const int4*)dst)[i];
        int* h = hist8 + copy * N;
        atomicAdd(&h[d.x], 1);
        atomicAdd(&h[d.y], 1);
        atomicAdd(&h[d.z], 1);
        atomicAdd(&h[d.w], 1);
    }
    if (i == 0) {
        for (int j = E4 * 4; j < E; ++j) atomicAdd(&hist8[dst[j]], 1);   // copy 0
    }
}

// per node: copy-offsets, degree, dinv; block sums of PADDED degree
__global__ __launch_bounds__(256) void k_xcdoff_bsum(int* __restrict__ hist8, int* __restrict__ degi,
                                                     float* __restrict__ dinv, int* __restrict__ bsum, int N) {
    __shared__ int ws[4];
    int t = threadIdx.x;
    int i = blockIdx.x * 256 + t;
    int pd = 0;
    if (i < N) {
        int run = 0;
#pragma unroll
        for (int j = 0; j < 8; ++j) {
            int c = hist8[j * N + i];
            hist8[j * N + i] = run;
            run += c;
        }
        degi[i] = run;
        dinv[i] = rsqrtf((float)run + 1.0f);
        pd = padded8(run);
    }
    int v = pd;
#pragma unroll
    for (int off = 1; off < 64; off <<= 1) v += __shfl_xor(v, off, 64);
    if ((t & 63) == 0) ws[t >> 6] = v;
    __syncthreads();
    if (t == 0) bsum[blockIdx.x] = ws[0] + ws[1] + ws[2] + ws[3];
}

// block 0: scan block sums -> boff, prow[N]=total; blocks 1..24: weight prep
__global__ __launch_bounds__(1024) void k_boff_wprep(const int* __restrict__ bsum, int* __restrict__ boff,
                                                     int nb, int* __restrict__ prow, int N,
                                                     const float* __restrict__ W2, const float* __restrict__ Wlin,
                                                     unsigned* __restrict__ wswz) {
    int t = threadIdx.x;
    if (blockIdx.x == 0) {
        __shared__ int s[1024];
        s[t] = (t < nb) ? bsum[t] : 0;
        __syncthreads();
        for (int off = 1; off < 1024; off <<= 1) {
            int v = (t >= off) ? s[t - off] : 0;
            __syncthreads();
            s[t] += v;
            __syncthreads();
        }
        if (t < nb) boff[t] = (t == 0) ? 0 : s[t - 1];
        if (t == 0) prow[N] = s[1023];
    } else {
        int tid = (blockIdx.x - 1) * 1024 + t;       // 0..24575 = 3*8192
        int m = tid >> 13;
        int r = tid & 8191;
        int jp = r & 3;
        int lane = (r >> 2) & 63;
        int ct = (r >> 8) & 7;
        int kc = r >> 11;
        int k0 = kc * 32 + (lane >> 4) * 8 + 2 * jp;
        int n = ct * 16 + (lane & 15);
        const float* srcp = (m == 0) ? W2 : (Wlin + (m - 1) * 16384);
        wswz[tid] = f2bf_pk(srcp[k0 * 128 + n], srcp[(k0 + 1) * 128 + n]);
    }
}

__global__ __launch_bounds__(256) void k_scan_final(const int* __restrict__ degi, const int* __restrict__ boff,
                                                    int* __restrict__ prow, int N) {
    __shared__ int s[256];
    int t = threadIdx.x;
    int i = blockIdx.x * 256 + t;
    int pd = (i < N) ? padded8(degi[i]) : 0;
    s[t] = pd;
    __syncthreads();
    for (int off = 1; off < 256; off <<= 1) {
        int v = (t >= off) ? s[t - off] : 0;
        __syncthreads();
        s[t] += v;
        __syncthreads();
    }
    if (i < N) prow[i] = boff[blockIdx.x] + ((t == 0) ? 0 : s[t - 1]);
}

// scatter into padded CSR (int4 groups, SAME copy mapping as k_degree8) + pad fill
__global__ __launch_bounds__(256) void k_scatter_fill(const int* __restrict__ src, const int* __restrict__ dst,
                                                      int E, const int* __restrict__ prow,
                                                      int* __restrict__ hist8, const int* __restrict__ degi,
                                                      int2* __restrict__ coleid, int N, int eb4) {
    int t = threadIdx.x;
    if ((int)blockIdx.x < eb4) {
        int i = blockIdx.x * 256 + t;
        int copy = blockIdx.x & 7;
        int E4 = E >> 2;
        if (i < E4) {
            int4 d = ((const int4*)dst)[i];
            int4 s4 = ((const int4*)src)[i];
            int* h = hist8 + copy * N;
            int e = i * 4;
            int off;
            off = atomicAdd(&h[d.x], 1); coleid[prow[d.x] + off] = make_int2(s4.x, e + 0);
            off = atomicAdd(&h[d.y], 1); coleid[prow[d.y] + off] = make_int2(s4.y, e + 1);
            off = atomicAdd(&h[d.z], 1); coleid[prow[d.z] + off] = make_int2(s4.z, e + 2);
            off = atomicAdd(&h[d.w], 1); coleid[prow[d.w] + off] = make_int2(s4.w, e + 3);
        }
        if (i == 0) {
            for (int j = (E >> 2) * 4; j < E; ++j) {
                int d = dst[j];
                int off = atomicAdd(&hist8[d], 1);   // copy 0
                coleid[prow[d] + off] = make_int2(src[j], j);
            }
        }
    } else {
        int n = (blockIdx.x - eb4) * 256 + t;
        if (n < N) {
            int lo = prow[n];
            int deg = degi[n];
            int pd = padded8(deg);
            for (int j = deg; j < pd; ++j) coleid[lo + j] = make_int2(N, 0);
        }
        if ((int)blockIdx.x == eb4 && t == 0) {
            int P = prow[N];
            for (int j = 0; j < 16; ++j) coleid[P + j] = make_int2(N, 0);
        }
    }
}

// ---- layer-1 transform  g1 = bf16(dinv * (x @ W1)) + zero sentinel row ----

__global__ __launch_bounds__(256) void k_xform1(const float* __restrict__ x, const float* __restrict__ W1,
                                                const float* __restrict__ dinv, unsigned* __restrict__ g, int N) {
    __shared__ float Ws[8 * D];
    int t = threadIdx.x;
    for (int i = t; i < 8 * D; i += 256) Ws[i] = W1[i];
    __syncthreads();
    int node = blockIdx.x * 4 + (t >> 6);
    int l = t & 63;
    if (node < N) {
        float s0 = 0.f, s1 = 0.f;
#pragma unroll
        for (int k = 0; k < 8; ++k) {
            float xv = x[node * 8 + k];
            s0 += xv * Ws[k * D + 2 * l];
            s1 += xv * Ws[k * D + 2 * l + 1];
        }
        float di = dinv[node];
        g[node * 64 + l] = f2bf_pk(s0 * di, s1 * di);
    }
    if (blockIdx.x == 0 && t < 64) g[(size_t)N * 64 + t] = 0;   // zero sentinel row
}

// ---- Aggregation: wave/node; padded CSR, no predication; depth-2 row pipeline ----

__global__ __launch_bounds__(256) void k_agg(const uint4* __restrict__ g, const int* __restrict__ prow,
                                             const int2* __restrict__ coleid, const float* __restrict__ dinv,
                                             const float* __restrict__ bias, uint4* __restrict__ h, int N) {
    int wave = (blockIdx.x * blockDim.x + threadIdx.x) >> 6;
    int lane = threadIdx.x & 63;
    if (wave >= N) return;
    int i = wave;
    int sub = lane >> 4;
    int r = lane & 15;
    float acc[8];
#pragma unroll
    for (int j = 0; j < 8; ++j) acc[j] = 0.f;
    int lo = prow[i], hiP = prow[i + 1];

    int idx = lo + sub;
    int c0 = coleid[idx].x;
    int c1 = (idx + 4 < hiP) ? coleid[idx + 4].x : N;
    int c2 = (idx + 8 < hiP) ? coleid[idx + 8].x : N;
    uint4 v0 = g[c0 * 16 + r];
    uint4 v1 = g[c1 * 16 + r];

    for (int k = lo; k < hiP; k += 4) {
        int c3 = (idx + 12 < hiP) ? coleid[idx + 12].x : N;   // col t+3
        uint4 v2 = g[c2 * 16 + r];                            // row t+2 (addr ready)
        float2 p;
        p = bf2f2(v0.x); acc[0] += p.x; acc[1] += p.y;
        p = bf2f2(v0.y); acc[2] += p.x; acc[3] += p.y;
        p = bf2f2(v0.z); acc[4] += p.x; acc[5] += p.y;
        p = bf2f2(v0.w); acc[6] += p.x; acc[7] += p.y;
        v0 = v1; v1 = v2; c2 = c3; idx += 4;
    }
#pragma unroll
    for (int j = 0; j < 8; ++j) {
        acc[j] += __shfl_xor(acc[j], 16, 64);
        acc[j] += __shfl_xor(acc[j], 32, 64);
    }
    if (sub == 0) {
        uint4 sv = g[i * 16 + r];   // self term
        float2 p;
        p = bf2f2(sv.x); acc[0] += p.x; acc[1] += p.y;
        p = bf2f2(sv.y); acc[2] += p.x; acc[3] += p.y;
        p = bf2f2(sv.z); acc[4] += p.x; acc[5] += p.y;
        p = bf2f2(sv.w); acc[6] += p.x; acc[7] += p.y;
        float di = dinv[i];
        float4 b0 = ((const float4*)bias)[r * 2];
        float4 b1 = ((const float4*)bias)[r * 2 + 1];
        float r0 = fmaxf(acc[0] * di + b0.x, 0.f);
        float r1 = fmaxf(acc[1] * di + b0.y, 0.f);
        float r2 = fmaxf(acc[2] * di + b0.z, 0.f);
        float r3 = fmaxf(acc[3] * di + b0.w, 0.f);
        float r4 = fmaxf(acc[4] * di + b1.x, 0.f);
        float r5 = fmaxf(acc[5] * di + b1.y, 0.f);
        float r6 = fmaxf(acc[6] * di + b1.z, 0.f);
        float r7 = fmaxf(acc[7] * di + b1.w, 0.f);
        uint4 o;
        o.x = f2bf_pk(r0, r1);
        o.y = f2bf_pk(r2, r3);
        o.z = f2bf_pk(r4, r5);
        o.w = f2bf_pk(r6, r7);
        h[i * 16 + r] = o;
    }
}

// ---- MFMA node GEMM (single): out_bf16 = pack((h @ W) * dinv? + bias?) + zero row ----

__global__ __launch_bounds__(256) void k_gemm_mfma(const uint4* __restrict__ wswz, const uint4* __restrict__ in,
                                                   const float* __restrict__ bias, const float* __restrict__ dinv,
                                                   u16* __restrict__ out, int N) {
    int t = threadIdx.x;
    int wv = t >> 6;
    int lane = t & 63;
    int quad = lane >> 4;
    int l15 = lane & 15;
    int nbase = blockIdx.x * 64 + wv * 16;

    f32x4 acc[8];
#pragma unroll
    for (int ct = 0; ct < 8; ++ct) acc[ct] = (f32x4){0.f, 0.f, 0.f, 0.f};

    int arow = nbase + l15;
    const uint4* arowp = in + (size_t)(arow < N ? arow : 0) * 16;

#pragma unroll
    for (int kc = 0; kc < 4; ++kc) {
        BU a; a.u = arowp[kc * 4 + quad];
#pragma unroll
        for (int ct = 0; ct < 8; ++ct) {
            BU b; b.u = wswz[(kc * 8 + ct) * 64 + lane];
            acc[ct] = __builtin_amdgcn_mfma_f32_16x16x32_bf16(a.s, b.s, acc[ct], 0, 0, 0);
        }
    }
#pragma unroll
    for (int reg = 0; reg < 4; ++reg) {
        int node = nbase + quad * 4 + reg;
        if (node >= N) continue;
        float sc = dinv ? dinv[node] : 1.0f;
#pragma unroll
        for (int ct = 0; ct < 8; ++ct) {
            int colj = ct * 16 + l15;
            float v = acc[ct][reg] * sc + (bias ? bias[colj] : 0.f);
            out[(size_t)node * 128 + colj] = f2bf(v);
        }
    }
    if (blockIdx.x == 0 && t < 64) ((unsigned*)out)[(size_t)N * 64 + t] = 0;   // zero sentinel row
}

// ---- Fused dual MFMA GEMM: a = h@Wtop ; c = h@Wbot + blin ----

__global__ __launch_bounds__(256) void k_gemm_dual(const uint4* __restrict__ wA, const uint4* __restrict__ wC,
                                                   const uint4* __restrict__ in, const float* __restrict__ biasC,
                                                   u16* __restrict__ outA, u16* __restrict__ outC, int N) {
    int t = threadIdx.x;
    int wv = t >> 6;
    int lane = t & 63;
    int quad = lane >> 4;
    int l15 = lane & 15;
    int nbase = blockIdx.x * 64 + wv * 16;

    f32x4 accA[8], accC[8];
#pragma unroll
    for (int ct = 0; ct < 8; ++ct) {
        accA[ct] = (f32x4){0.f, 0.f, 0.f, 0.f};
        accC[ct] = (f32x4){0.f, 0.f, 0.f, 0.f};
    }

    int arow = nbase + l15;
    const uint4* arowp = in + (size_t)(arow < N ? arow : 0) * 16;

#pragma unroll
    for (int kc = 0; kc < 4; ++kc) {
        BU a; a.u = arowp[kc * 4 + quad];
#pragma unroll
        for (int ct = 0; ct < 8; ++ct) {
            BU bA; bA.u = wA[(kc * 8 + ct) * 64 + lane];
            accA[ct] = __builtin_amdgcn_mfma_f32_16x16x32_bf16(a.s, bA.s, accA[ct], 0, 0, 0);
            BU bC; bC.u = wC[(kc * 8 + ct) * 64 + lane];
            accC[ct] = __builtin_amdgcn_mfma_f32_16x16x32_bf16(a.s, bC.s, accC[ct], 0, 0, 0);
        }
    }
#pragma unroll
    for (int reg = 0; reg < 4; ++reg) {
        int node = nbase + quad * 4 + reg;
        if (node >= N) continue;
#pragma unroll
        for (int ct = 0; ct < 8; ++ct) {
            int colj = ct * 16 + l15;
            outA[(size_t)node * 128 + colj] = f2bf(accA[ct][reg]);
            outC[(size_t)node * 128 + colj] = f2bf(accC[ct][reg] + biasC[colj]);
        }
    }
    if (blockIdx.x == 0 && t < 64) ((unsigned*)outA)[(size_t)N * 64 + t] = 0;  // zero sentinel row
}

// ---- Edge output: padded CSR, depth-2 row pipeline (3-stage eid chain) ----

__global__ __launch_bounds__(256) void k_edge(const uint4* __restrict__ a, const uint4* __restrict__ c,
                                              const int* __restrict__ prow, const int* __restrict__ degi,
                                              const int2* __restrict__ coleid,
                                              const float* __restrict__ Wfin, const float* __restrict__ bfin,
                                              float* __restrict__ out, int N) {
    int wave = (blockIdx.x * blockDim.x + threadIdx.x) >> 6;
    int lane = threadIdx.x & 63;
    if (wave >= N) return;
    int d = wave;
    int g = lane >> 4;
    int r = lane & 15;

    float wf0[8], wf1[8];
    const float4* wvp = (const float4*)Wfin;
#pragma unroll
    for (int q = 0; q < 4; ++q) {
        float4 m = wvp[r * 4 + q];
        wf0[2 * q] = m.x; wf1[2 * q] = m.y;
        wf0[2 * q + 1] = m.z; wf1[2 * q + 1] = m.w;
    }
    float bf0 = bfin[0], bf1 = bfin[1];

    float cf[8];
    {
        uint4 cv = c[d * 16 + r];
        float2 p;
        p = bf2f2(cv.x); cf[0] = p.x; cf[1] = p.y;
        p = bf2f2(cv.y); cf[2] = p.x; cf[3] = p.y;
        p = bf2f2(cv.z); cf[4] = p.x; cf[5] = p.y;
        p = bf2f2(cv.w); cf[6] = p.x; cf[7] = p.y;
    }

    int lo = prow[d], hiP = prow[d + 1];
    int deg = degi[d];

    int idx = lo + g;
    int2 q0 = coleid[idx];
    int2 q1 = coleid[idx + 4];
    int c1 = (idx + 4 < hiP) ? q1.x : N;
    int2 q2 = coleid[idx + 8];
    int c2 = (idx + 8 < hiP) ? q2.x : N;
    int e0 = q0.y, e1 = q1.y, e2 = q2.y;
    uint4 v0 = a[q0.x * 16 + r];
    uint4 v1 = a[c1 * 16 + r];

    int rel = g;   // edge index within node for validity
    for (int k = lo; k < hiP; k += 4) {
        int2 q3 = coleid[idx + 12];
        int c3 = (idx + 12 < hiP) ? q3.x : N;
        uint4 v2 = a[c2 * 16 + r];                  // row t+2
        float p0 = 0.f, p1 = 0.f;
        float2 p;
        float z;
        p = bf2f2(v0.x);
        z = fmaxf(p.x + cf[0], 0.f); p0 += z * wf0[0]; p1 += z * wf1[0];
        z = fmaxf(p.y + cf[1], 0.f); p0 += z * wf0[1]; p1 += z * wf1[1];
        p = bf2f2(v0.y);
        z = fmaxf(p.x + cf[2], 0.f); p0 += z * wf0[2]; p1 += z * wf1[2];
        z = fmaxf(p.y + cf[3], 0.f); p0 += z * wf0[3]; p1 += z * wf1[3];
        p = bf2f2(v0.z);
        z = fmaxf(p.x + cf[4], 0.f); p0 += z * wf0[4]; p1 += z * wf1[4];
        z = fmaxf(p.y + cf[5], 0.f); p0 += z * wf0[5]; p1 += z * wf1[5];
        p = bf2f2(v0.w);
        z = fmaxf(p.x + cf[6], 0.f); p0 += z * wf0[6]; p1 += z * wf1[6];
        z = fmaxf(p.y + cf[7], 0.f); p0 += z * wf0[7]; p1 += z * wf1[7];
        p0 += __shfl_xor(p0, 1, 64);
        p0 += __shfl_xor(p0, 2, 64);
        p0 += __shfl_xor(p0, 4, 64);
        p0 += __shfl_xor(p0, 8, 64);
        p1 += __shfl_xor(p1, 1, 64);
        p1 += __shfl_xor(p1, 2, 64);
        p1 += __shfl_xor(p1, 4, 64);
        p1 += __shfl_xor(p1, 8, 64);
        if (r == 0 && rel < deg) {
            float l0 = p0 + bf0, l1 = p1 + bf1;
            float m = fmaxf(l0, l1);
            float lse = m + __logf(__expf(l0 - m) + __expf(l1 - m));
            *((float2*)(out + 2 * (size_t)e0)) = make_float2(l0 - lse, l1 - lse);
        }
        v0 = v1; v1 = v2;
        e0 = e1; e1 = e2; e2 = q3.y;
        c2 = c3; idx += 4; rel += 4;
    }
}

extern "C" void kernel_launch(void* const* d_in, const int* in_sizes, int n_in,
                              void* d_out, int out_size, void* d_ws, size_t ws_size,
                              hipStream_t stream) {
    const float* x     = (const float*)d_in[0];
    const int*   ei    = (const int*)d_in[1];
    const float* W1    = (const float*)d_in[2];
    const float* b1    = (const float*)d_in[3];
    const float* W2    = (const float*)d_in[4];
    const float* b2    = (const float*)d_in[5];
    const float* Wlin1 = (const float*)d_in[6];
    const float* blin1 = (const float*)d_in[7];
    const float* Wfin  = (const float*)d_in[8];
    const float* bfin  = (const float*)d_in[9];
    float* out = (float*)d_out;

    int N = in_sizes[0] / 8;
    int E = in_sizes[1] / 2;
    const int* src = ei;
    const int* dst = ei + E;
    int nb = (N + 255) / 256;
    int eb4 = (E / 4 + 255) / 256;

    char* w = (char*)d_ws;
    int* hist8 = (int*)w;     w += (size_t)8 * N * 4;
    int* degi = (int*)w;      w += (size_t)N * 4;
    int* prow = (int*)w;      w += (size_t)(N + 1) * 4;
    float* dinv = (float*)w;  w += (size_t)N * 4;
    int* bsum = (int*)w;      w += (size_t)nb * 4;
    int* boff = (int*)w;      w += (size_t)nb * 4;
    w = (char*)(((uintptr_t)w + 255) & ~(uintptr_t)255);
    int2* coleid = (int2*)w;  w += ((size_t)E + 8 * (size_t)N + 64) * 8;
    unsigned* wswz = (unsigned*)w; w += (size_t)3 * 8192 * 4;
    unsigned* bufG = (unsigned*)w; w += (size_t)(N + 1) * 64 * 4;   // + zero sentinel row
    unsigned* bufH = (unsigned*)w; w += (size_t)N * 64 * 4;
    unsigned* bufA = (unsigned*)w; w += (size_t)(N + 1) * 64 * 4;   // + zero sentinel row
    unsigned* bufC = (unsigned*)w; w += (size_t)N * 64 * 4;

    hipMemsetAsync(hist8, 0, (size_t)8 * N * 4, stream);

    k_degree8<<<eb4, 256, 0, stream>>>(dst, E, hist8, N);
    k_xcdoff_bsum<<<nb, 256, 0, stream>>>(hist8, degi, dinv, bsum, N);
    k_boff_wprep<<<25, 1024, 0, stream>>>(bsum, boff, nb, prow, N, W2, Wlin1, wswz);
    k_scan_final<<<nb, 256, 0, stream>>>(degi, boff, prow, N);
    k_scatter_fill<<<eb4 + nb, 256, 0, stream>>>(src, dst, E, prow, hist8, degi, coleid, N, eb4);

    // layer 1
    k_xform1<<<(N + 3) / 4, 256, 0, stream>>>(x, W1, dinv, bufG, N);
    k_agg<<<(N + 3) / 4, 256, 0, stream>>>((const uint4*)bufG, prow, coleid, dinv, b1, (uint4*)bufH, N);

    // layer 2: g2 = dinv*(h1@W2)
    int mblocks = (N + 63) / 64;
    k_gemm_mfma<<<mblocks, 256, 0, stream>>>((const uint4*)wswz, (const uint4*)bufH,
                                             nullptr, dinv, (u16*)bufG, N);
    k_agg<<<(N + 3) / 4, 256, 0, stream>>>((const uint4*)bufG, prow, coleid, dinv, b2, (uint4*)bufH, N);

    // edge MLP factorization: a = h2@Wtop ; c = h2@Wbot + blin1
    k_gemm_dual<<<mblocks, 256, 0, stream>>>((const uint4*)(wswz + 8192), (const uint4*)(wswz + 16384),
                                             (const uint4*)bufH, blin1, (u16*)bufA, (u16*)bufC, N);

    k_edge<<<(N + 3) / 4, 256, 0, stream>>>((const uint4*)bufA, (const uint4*)bufC,
                                            prow, degi, coleid, Wfin, bfin, out, N);
}

// Round 10
// 302.837 us; speedup vs baseline: 2.3119x; 1.0616x over previous
//
#include <hip/hip_runtime.h>
#include <stdint.h>
#include <math.h>

#define D 128

typedef unsigned short u16;
typedef __attribute__((ext_vector_type(8))) short bf16x8;
typedef __attribute__((ext_vector_type(4))) float f32x4;
typedef __attribute__((ext_vector_type(2))) float f32x2;

union BU { uint4 u; bf16x8 s; };

// bf16 pack/unpack (RNE)
__device__ __forceinline__ unsigned f2bf_pk(float a, float b) {
    union { float f; unsigned u; } x, y; x.f = a; y.f = b;
    unsigned ra = x.u + 0x7FFF + ((x.u >> 16) & 1);
    unsigned rb = y.u + 0x7FFF + ((y.u >> 16) & 1);
    return (ra >> 16) | (rb & 0xFFFF0000u);
}
__device__ __forceinline__ u16 f2bf(float f) {
    union { float f; unsigned u; } x; x.f = f;
    unsigned r = x.u + 0x7FFF + ((x.u >> 16) & 1);
    return (u16)(r >> 16);
}
__device__ __forceinline__ f32x2 bf2f2v(unsigned u) {
    union { unsigned w[2]; f32x2 v; } t;
    t.w[0] = u << 16; t.w[1] = u & 0xFFFF0000u;
    return t.v;
}
__device__ __forceinline__ f32x2 vmax0(f32x2 a) {
    return __builtin_elementwise_max(a, (f32x2)(0.f));
}
__device__ __forceinline__ int padded8(int deg) {
    int pd = (deg + 7) & ~7;
    return pd ? pd : 8;
}

// ---- CSR build: 8-way privatized histogram, int4-vectorized ----

__global__ __launch_bounds__(256) void k_degree8(const int* __restrict__ dst, int E,
                                                 int* __restrict__ hist8, int N) {
    int i = blockIdx.x * 256 + threadIdx.x;
    int copy = blockIdx.x & 7;
    int E4 = E >> 2;
    if (i < E4) {
        int4 d = ((const int4*)dst)[i];
        int* h = hist8 + copy * N;
        atomicAdd(&h[d.x], 1);
        atomicAdd(&h[d.y], 1);
        atomicAdd(&h[d.z], 1);
        atomicAdd(&h[d.w], 1);
    }
    if (i == 0) {
        for (int j = E4 * 4; j < E; ++j) atomicAdd(&hist8[dst[j]], 1);   // copy 0
    }
}

__global__ __launch_bounds__(256) void k_xcdoff_bsum(int* __restrict__ hist8, int* __restrict__ degi,
                                                     float* __restrict__ dinv, int* __restrict__ bsum, int N) {
    __shared__ int ws[4];
    int t = threadIdx.x;
    int i = blockIdx.x * 256 + t;
    int pd = 0;
    if (i < N) {
        int run = 0;
#pragma unroll
        for (int j = 0; j < 8; ++j) {
            int c = hist8[j * N + i];
            hist8[j * N + i] = run;
            run += c;
        }
        degi[i] = run;
        dinv[i] = rsqrtf((float)run + 1.0f);
        pd = padded8(run);
    }
    int v = pd;
#pragma unroll
    for (int off = 1; off < 64; off <<= 1) v += __shfl_xor(v, off, 64);
    if ((t & 63) == 0) ws[t >> 6] = v;
    __syncthreads();
    if (t == 0) bsum[blockIdx.x] = ws[0] + ws[1] + ws[2] + ws[3];
}

__global__ __launch_bounds__(1024) void k_boff_wprep(const int* __restrict__ bsum, int* __restrict__ boff,
                                                     int nb, int* __restrict__ prow, int N,
                                                     const float* __restrict__ W2, const float* __restrict__ Wlin,
                                                     unsigned* __restrict__ wswz) {
    int t = threadIdx.x;
    if (blockIdx.x == 0) {
        __shared__ int s[1024];
        s[t] = (t < nb) ? bsum[t] : 0;
        __syncthreads();
        for (int off = 1; off < 1024; off <<= 1) {
            int v = (t >= off) ? s[t - off] : 0;
            __syncthreads();
            s[t] += v;
            __syncthreads();
        }
        if (t < nb) boff[t] = (t == 0) ? 0 : s[t - 1];
        if (t == 0) prow[N] = s[1023];
    } else {
        int tid = (blockIdx.x - 1) * 1024 + t;       // 0..24575 = 3*8192
        int m = tid >> 13;
        int r = tid & 8191;
        int jp = r & 3;
        int lane = (r >> 2) & 63;
        int ct = (r >> 8) & 7;
        int kc = r >> 11;
        int k0 = kc * 32 + (lane >> 4) * 8 + 2 * jp;
        int n = ct * 16 + (lane & 15);
        const float* srcp = (m == 0) ? W2 : (Wlin + (m - 1) * 16384);
        wswz[tid] = f2bf_pk(srcp[k0 * 128 + n], srcp[(k0 + 1) * 128 + n]);
    }
}

__global__ __launch_bounds__(256) void k_scan_final(const int* __restrict__ degi, const int* __restrict__ boff,
                                                    int* __restrict__ prow, int N) {
    __shared__ int s[256];
    int t = threadIdx.x;
    int i = blockIdx.x * 256 + t;
    int pd = (i < N) ? padded8(degi[i]) : 0;
    s[t] = pd;
    __syncthreads();
    for (int off = 1; off < 256; off <<= 1) {
        int v = (t >= off) ? s[t - off] : 0;
        __syncthreads();
        s[t] += v;
        __syncthreads();
    }
    if (i < N) prow[i] = boff[blockIdx.x] + ((t == 0) ? 0 : s[t - 1]);
}

__global__ __launch_bounds__(256) void k_scatter_fill(const int* __restrict__ src, const int* __restrict__ dst,
                                                      int E, const int* __restrict__ prow,
                                                      int* __restrict__ hist8, const int* __restrict__ degi,
                                                      int2* __restrict__ coleid, int N, int eb4) {
    int t = threadIdx.x;
    if ((int)blockIdx.x < eb4) {
        int i = blockIdx.x * 256 + t;
        int copy = blockIdx.x & 7;
        int E4 = E >> 2;
        if (i < E4) {
            int4 d = ((const int4*)dst)[i];
            int4 s4 = ((const int4*)src)[i];
            int* h = hist8 + copy * N;
            int e = i * 4;
            int off;
            off = atomicAdd(&h[d.x], 1); coleid[prow[d.x] + off] = make_int2(s4.x, e + 0);
            off = atomicAdd(&h[d.y], 1); coleid[prow[d.y] + off] = make_int2(s4.y, e + 1);
            off = atomicAdd(&h[d.z], 1); coleid[prow[d.z] + off] = make_int2(s4.z, e + 2);
            off = atomicAdd(&h[d.w], 1); coleid[prow[d.w] + off] = make_int2(s4.w, e + 3);
        }
        if (i == 0) {
            for (int j = (E >> 2) * 4; j < E; ++j) {
                int d = dst[j];
                int off = atomicAdd(&hist8[d], 1);   // copy 0
                coleid[prow[d] + off] = make_int2(src[j], j);
            }
        }
    } else {
        int n = (blockIdx.x - eb4) * 256 + t;
        if (n < N) {
            int lo = prow[n];
            int deg = degi[n];
            int pd = padded8(deg);
            for (int j = deg; j < pd; ++j) coleid[lo + j] = make_int2(N, 0);
        }
        if ((int)blockIdx.x == eb4 && t == 0) {
            int P = prow[N];
            for (int j = 0; j < 16; ++j) coleid[P + j] = make_int2(N, 0);
        }
    }
}

// ---- layer-1 transform  g1 = bf16(dinv * (x @ W1)) + zero sentinel row ----

__global__ __launch_bounds__(256) void k_xform1(const float* __restrict__ x, const float* __restrict__ W1,
                                                const float* __restrict__ dinv, unsigned* __restrict__ g, int N) {
    __shared__ float Ws[8 * D];
    int t = threadIdx.x;
    for (int i = t; i < 8 * D; i += 256) Ws[i] = W1[i];
    __syncthreads();
    int node = blockIdx.x * 4 + (t >> 6);
    int l = t & 63;
    if (node < N) {
        float s0 = 0.f, s1 = 0.f;
#pragma unroll
        for (int k = 0; k < 8; ++k) {
            float xv = x[node * 8 + k];
            s0 += xv * Ws[k * D + 2 * l];
            s1 += xv * Ws[k * D + 2 * l + 1];
        }
        float di = dinv[node];
        g[node * 64 + l] = f2bf_pk(s0 * di, s1 * di);
    }
    if (blockIdx.x == 0 && t < 64) g[(size_t)N * 64 + t] = 0;   // zero sentinel row
}

// ---- Fused aggregation + MFMA GEMM ----
// Block = 4 waves, 16-node tile. Each wave aggregates 4 nodes (CSR gather, packed f32x2 math),
// stages h rows (bf16) in LDS; then each wave MFMAs the tile against 2 column-tiles of W.
// DUAL=false: out0 = bf16(dinv * (h@W0))            (layer-2 g2)
// DUAL=true : out0 = bf16(h@W0) ; out1 = bf16(h@W1 + bias1)   (edge-MLP a,c)

#define HROW 136   // u16 per LDS row (128 + 8 pad -> 272 B row stride)

template <bool DUAL>
__global__ __launch_bounds__(256) void k_aggemm(const uint4* __restrict__ g, const int* __restrict__ prow,
                                                const int2* __restrict__ coleid, const float* __restrict__ dinv,
                                                const float* __restrict__ biasH,
                                                const uint4* __restrict__ wB0, const uint4* __restrict__ wB1,
                                                const float* __restrict__ bias1,
                                                u16* __restrict__ out0, u16* __restrict__ out1, int N) {
    __shared__ u16 hs[16 * HROW];
    int t = threadIdx.x;
    int wv = t >> 6;
    int lane = t & 63;
    int sub = lane >> 4;
    int r = lane & 15;
    int base = blockIdx.x * 16;

    // ---- aggregation phase: 4 nodes per wave ----
    for (int nd = 0; nd < 4; ++nd) {
        int i = base + wv * 4 + nd;
        int lrow = wv * 4 + nd;
        if (i < N) {
            f32x2 acc2[4];
#pragma unroll
            for (int j = 0; j < 4; ++j) acc2[j] = (f32x2)(0.f);
            int lo = prow[i], hiP = prow[i + 1];
            int idx = lo + sub;
            int c0 = coleid[idx].x;
            int c1 = (idx + 4 < hiP) ? coleid[idx + 4].x : N;
            int c2 = (idx + 8 < hiP) ? coleid[idx + 8].x : N;
            uint4 v0 = g[c0 * 16 + r];
            uint4 v1 = g[c1 * 16 + r];
            for (int k = lo; k < hiP; k += 4) {
                int c3 = (idx + 12 < hiP) ? coleid[idx + 12].x : N;
                uint4 v2 = g[c2 * 16 + r];
                acc2[0] += bf2f2v(v0.x);
                acc2[1] += bf2f2v(v0.y);
                acc2[2] += bf2f2v(v0.z);
                acc2[3] += bf2f2v(v0.w);
                v0 = v1; v1 = v2; c2 = c3; idx += 4;
            }
#pragma unroll
            for (int j = 0; j < 4; ++j) {
                acc2[j].x += __shfl_xor(acc2[j].x, 16, 64);
                acc2[j].y += __shfl_xor(acc2[j].y, 16, 64);
                acc2[j].x += __shfl_xor(acc2[j].x, 32, 64);
                acc2[j].y += __shfl_xor(acc2[j].y, 32, 64);
            }
            if (sub == 0) {
                uint4 sv = g[i * 16 + r];   // self term
                acc2[0] += bf2f2v(sv.x);
                acc2[1] += bf2f2v(sv.y);
                acc2[2] += bf2f2v(sv.z);
                acc2[3] += bf2f2v(sv.w);
                float di = dinv[i];
                float4 b0 = ((const float4*)biasH)[r * 2];
                float4 b1v = ((const float4*)biasH)[r * 2 + 1];
                float r0 = fmaxf(acc2[0].x * di + b0.x, 0.f);
                float r1 = fmaxf(acc2[0].y * di + b0.y, 0.f);
                float r2 = fmaxf(acc2[1].x * di + b0.z, 0.f);
                float r3 = fmaxf(acc2[1].y * di + b0.w, 0.f);
                float r4 = fmaxf(acc2[2].x * di + b1v.x, 0.f);
                float r5 = fmaxf(acc2[2].y * di + b1v.y, 0.f);
                float r6 = fmaxf(acc2[3].x * di + b1v.z, 0.f);
                float r7 = fmaxf(acc2[3].y * di + b1v.w, 0.f);
                uint4 o;
                o.x = f2bf_pk(r0, r1);
                o.y = f2bf_pk(r2, r3);
                o.z = f2bf_pk(r4, r5);
                o.w = f2bf_pk(r6, r7);
                *(uint4*)(hs + lrow * HROW + r * 8) = o;
            }
        } else if (sub == 0) {
            *(uint4*)(hs + lrow * HROW + r * 8) = make_uint4(0, 0, 0, 0);
        }
    }
    __syncthreads();

    // ---- GEMM phase: wave wv handles column-tiles ct0, ct0+1 ----
    int quad = lane >> 4;
    int l15 = lane & 15;
    int ct0 = wv * 2;

    f32x4 accA[2], accB[2];
#pragma unroll
    for (int q = 0; q < 2; ++q) { accA[q] = (f32x4){0.f, 0.f, 0.f, 0.f}; accB[q] = (f32x4){0.f, 0.f, 0.f, 0.f}; }

    const uint4* hrow = (const uint4*)(hs + l15 * HROW);
#pragma unroll
    for (int kc = 0; kc < 4; ++kc) {
        BU a; a.u = hrow[kc * 4 + quad];
#pragma unroll
        for (int q = 0; q < 2; ++q) {
            BU b0; b0.u = wB0[(kc * 8 + ct0 + q) * 64 + lane];
            accA[q] = __builtin_amdgcn_mfma_f32_16x16x32_bf16(a.s, b0.s, accA[q], 0, 0, 0);
            if (DUAL) {
                BU b1; b1.u = wB1[(kc * 8 + ct0 + q) * 64 + lane];
                accB[q] = __builtin_amdgcn_mfma_f32_16x16x32_bf16(a.s, b1.s, accB[q], 0, 0, 0);
            }
        }
    }
#pragma unroll
    for (int reg = 0; reg < 4; ++reg) {
        int node = base + quad * 4 + reg;
        if (node >= N) continue;
        float sc = DUAL ? 1.0f : dinv[node];
#pragma unroll
        for (int q = 0; q < 2; ++q) {
            int colj = (ct0 + q) * 16 + l15;
            out0[(size_t)node * 128 + colj] = f2bf(accA[q][reg] * sc);
            if (DUAL) out1[(size_t)node * 128 + colj] = f2bf(accB[q][reg] + bias1[colj]);
        }
    }
    if (blockIdx.x == 0 && t < 64) ((unsigned*)out0)[(size_t)N * 64 + t] = 0;   // zero sentinel row
}

// ---- Edge output: padded CSR, depth-2 pipeline, packed f32x2 math ----

__global__ __launch_bounds__(256) void k_edge(const uint4* __restrict__ a, const uint4* __restrict__ c,
                                              const int* __restrict__ prow, const int* __restrict__ degi,
                                              const int2* __restrict__ coleid,
                                              const float* __restrict__ Wfin, const float* __restrict__ bfin,
                                              float* __restrict__ out, int N) {
    int wave = (blockIdx.x * blockDim.x + threadIdx.x) >> 6;
    int lane = threadIdx.x & 63;
    if (wave >= N) return;
    int d = wave;
    int g = lane >> 4;
    int r = lane & 15;

    f32x2 wf0v[4], wf1v[4];
    const float4* wvp = (const float4*)Wfin;
#pragma unroll
    for (int q = 0; q < 4; ++q) {
        float4 m = wvp[r * 4 + q];
        wf0v[q] = (f32x2){m.x, m.z};
        wf1v[q] = (f32x2){m.y, m.w};
    }
    float bf0 = bfin[0], bf1 = bfin[1];

    f32x2 cf2[4];
    {
        uint4 cv = c[d * 16 + r];
        cf2[0] = bf2f2v(cv.x);
        cf2[1] = bf2f2v(cv.y);
        cf2[2] = bf2f2v(cv.z);
        cf2[3] = bf2f2v(cv.w);
    }

    int lo = prow[d], hiP = prow[d + 1];
    int deg = degi[d];

    int idx = lo + g;
    int2 q0 = coleid[idx];
    int2 q1 = coleid[idx + 4];
    int c1 = (idx + 4 < hiP) ? q1.x : N;
    int2 q2 = coleid[idx + 8];
    int c2 = (idx + 8 < hiP) ? q2.x : N;
    int e0 = q0.y, e1 = q1.y, e2 = q2.y;
    uint4 v0 = a[q0.x * 16 + r];
    uint4 v1 = a[c1 * 16 + r];

    int rel = g;
    for (int k = lo; k < hiP; k += 4) {
        int2 q3 = coleid[idx + 12];
        int c3 = (idx + 12 < hiP) ? q3.x : N;
        uint4 v2 = a[c2 * 16 + r];
        f32x2 p0v = (f32x2)(0.f), p1v = (f32x2)(0.f);
        f32x2 z;
        z = vmax0(bf2f2v(v0.x) + cf2[0]); p0v += z * wf0v[0]; p1v += z * wf1v[0];
        z = vmax0(bf2f2v(v0.y) + cf2[1]); p0v += z * wf0v[1]; p1v += z * wf1v[1];
        z = vmax0(bf2f2v(v0.z) + cf2[2]); p0v += z * wf0v[2]; p1v += z * wf1v[2];
        z = vmax0(bf2f2v(v0.w) + cf2[3]); p0v += z * wf0v[3]; p1v += z * wf1v[3];
        float p0 = p0v.x + p0v.y;
        float p1 = p1v.x + p1v.y;
        p0 += __shfl_xor(p0, 1, 64);
        p0 += __shfl_xor(p0, 2, 64);
        p0 += __shfl_xor(p0, 4, 64);
        p0 += __shfl_xor(p0, 8, 64);
        p1 += __shfl_xor(p1, 1, 64);
        p1 += __shfl_xor(p1, 2, 64);
        p1 += __shfl_xor(p1, 4, 64);
        p1 += __shfl_xor(p1, 8, 64);
        if (r == 0 && rel < deg) {
            float l0 = p0 + bf0, l1 = p1 + bf1;
            float m = fmaxf(l0, l1);
            float lse = m + __logf(__expf(l0 - m) + __expf(l1 - m));
            *((float2*)(out + 2 * (size_t)e0)) = make_float2(l0 - lse, l1 - lse);
        }
        v0 = v1; v1 = v2;
        e0 = e1; e1 = e2; e2 = q3.y;
        c2 = c3; idx += 4; rel += 4;
    }
}

extern "C" void kernel_launch(void* const* d_in, const int* in_sizes, int n_in,
                              void* d_out, int out_size, void* d_ws, size_t ws_size,
                              hipStream_t stream) {
    const float* x     = (const float*)d_in[0];
    const int*   ei    = (const int*)d_in[1];
    const float* W1    = (const float*)d_in[2];
    const float* b1    = (const float*)d_in[3];
    const float* W2    = (const float*)d_in[4];
    const float* b2    = (const float*)d_in[5];
    const float* Wlin1 = (const float*)d_in[6];
    const float* blin1 = (const float*)d_in[7];
    const float* Wfin  = (const float*)d_in[8];
    const float* bfin  = (const float*)d_in[9];
    float* out = (float*)d_out;

    int N = in_sizes[0] / 8;
    int E = in_sizes[1] / 2;
    const int* src = ei;
    const int* dst = ei + E;
    int nb = (N + 255) / 256;
    int eb4 = (E / 4 + 255) / 256;

    char* w = (char*)d_ws;
    int* hist8 = (int*)w;     w += (size_t)8 * N * 4;
    int* degi = (int*)w;      w += (size_t)N * 4;
    int* prow = (int*)w;      w += (size_t)(N + 1) * 4;
    float* dinv = (float*)w;  w += (size_t)N * 4;
    int* bsum = (int*)w;      w += (size_t)nb * 4;
    int* boff = (int*)w;      w += (size_t)nb * 4;
    w = (char*)(((uintptr_t)w + 255) & ~(uintptr_t)255);
    int2* coleid = (int2*)w;  w += ((size_t)E + 8 * (size_t)N + 64) * 8;
    unsigned* wswz = (unsigned*)w; w += (size_t)3 * 8192 * 4;
    unsigned* bufG = (unsigned*)w; w += (size_t)(N + 1) * 64 * 4;   // g1/g2 + sentinel
    unsigned* bufA = (unsigned*)w; w += (size_t)(N + 1) * 64 * 4;   // a + sentinel
    unsigned* bufC = (unsigned*)w; w += (size_t)N * 64 * 4;         // c
    unsigned* bufG2 = (unsigned*)w; w += (size_t)(N + 1) * 64 * 4;  // g2 + sentinel

    hipMemsetAsync(hist8, 0, (size_t)8 * N * 4, stream);

    k_degree8<<<eb4, 256, 0, stream>>>(dst, E, hist8, N);
    k_xcdoff_bsum<<<nb, 256, 0, stream>>>(hist8, degi, dinv, bsum, N);
    k_boff_wprep<<<25, 1024, 0, stream>>>(bsum, boff, nb, prow, N, W2, Wlin1, wswz);
    k_scan_final<<<nb, 256, 0, stream>>>(degi, boff, prow, N);
    k_scatter_fill<<<eb4 + nb, 256, 0, stream>>>(src, dst, E, prow, hist8, degi, coleid, N, eb4);

    // layer 1: g1
    k_xform1<<<(N + 3) / 4, 256, 0, stream>>>(x, W1, dinv, bufG, N);

    int ablocks = (N + 15) / 16;
    // fused: agg(g1)->h1 -> GEMM W2 -> g2 (dinv-scaled) + sentinel
    k_aggemm<false><<<ablocks, 256, 0, stream>>>((const uint4*)bufG, prow, coleid, dinv, b1,
                                                 (const uint4*)wswz, nullptr, nullptr,
                                                 (u16*)bufG2, nullptr, N);
    // fused: agg(g2)->h2 -> dual GEMM -> a (+sentinel), c (+blin1)
    k_aggemm<true><<<ablocks, 256, 0, stream>>>((const uint4*)bufG2, prow, coleid, dinv, b2,
                                                (const uint4*)(wswz + 8192), (const uint4*)(wswz + 16384),
                                                blin1, (u16*)bufA, (u16*)bufC, N);

    k_edge<<<(N + 3) / 4, 256, 0, stream>>>((const uint4*)bufA, (const uint4*)bufC,
                                            prow, degi, coleid, Wfin, bfin, out, N);
}

// Round 11
// 294.328 us; speedup vs baseline: 2.3787x; 1.0289x over previous
//
#include <hip/hip_runtime.h>
#include <stdint.h>
#include <math.h>

#define D 128

typedef unsigned short u16;
typedef __attribute__((ext_vector_type(8))) short bf16x8;
typedef __attribute__((ext_vector_type(4))) float f32x4;
typedef __attribute__((ext_vector_type(2))) float f32x2;

union BU { uint4 u; bf16x8 s; };

// bf16 pack/unpack (RNE)
__device__ __forceinline__ unsigned f2bf_pk(float a, float b) {
    union { float f; unsigned u; } x, y; x.f = a; y.f = b;
    unsigned ra = x.u + 0x7FFF + ((x.u >> 16) & 1);
    unsigned rb = y.u + 0x7FFF + ((y.u >> 16) & 1);
    return (ra >> 16) | (rb & 0xFFFF0000u);
}
__device__ __forceinline__ u16 f2bf(float f) {
    union { float f; unsigned u; } x; x.f = f;
    unsigned r = x.u + 0x7FFF + ((x.u >> 16) & 1);
    return (u16)(r >> 16);
}
__device__ __forceinline__ f32x2 bf2f2v(unsigned u) {
    union { unsigned w[2]; f32x2 v; } t;
    t.w[0] = u << 16; t.w[1] = u & 0xFFFF0000u;
    return t.v;
}
__device__ __forceinline__ f32x2 vmax0(f32x2 a) {
    return __builtin_elementwise_max(a, (f32x2)(0.f));
}
// pad to batch granularity 4 (0 allowed for isolated nodes)
__device__ __forceinline__ int padded4(int deg) {
    return (deg + 3) & ~3;
}

// ---- CSR build: 8-way privatized histogram, int4-vectorized ----

__global__ __launch_bounds__(256) void k_degree8(const int* __restrict__ dst, int E,
                                                 int* __restrict__ hist8, int N) {
    int i = blockIdx.x * 256 + threadIdx.x;
    int copy = blockIdx.x & 7;
    int E4 = E >> 2;
    if (i < E4) {
        int4 d = ((const int4*)dst)[i];
        int* h = hist8 + copy * N;
        atomicAdd(&h[d.x], 1);
        atomicAdd(&h[d.y], 1);
        atomicAdd(&h[d.z], 1);
        atomicAdd(&h[d.w], 1);
    }
    if (i == 0) {
        for (int j = E4 * 4; j < E; ++j) atomicAdd(&hist8[dst[j]], 1);   // copy 0
    }
}

__global__ __launch_bounds__(256) void k_xcdoff_bsum(int* __restrict__ hist8, int* __restrict__ degi,
                                                     float* __restrict__ dinv, int* __restrict__ bsum, int N) {
    __shared__ int ws[4];
    int t = threadIdx.x;
    int i = blockIdx.x * 256 + t;
    int pd = 0;
    if (i < N) {
        int run = 0;
#pragma unroll
        for (int j = 0; j < 8; ++j) {
            int c = hist8[j * N + i];
            hist8[j * N + i] = run;
            run += c;
        }
        degi[i] = run;
        dinv[i] = rsqrtf((float)run + 1.0f);
        pd = padded4(run);
    }
    int v = pd;
#pragma unroll
    for (int off = 1; off < 64; off <<= 1) v += __shfl_xor(v, off, 64);
    if ((t & 63) == 0) ws[t >> 6] = v;
    __syncthreads();
    if (t == 0) bsum[blockIdx.x] = ws[0] + ws[1] + ws[2] + ws[3];
}

__global__ __launch_bounds__(1024) void k_boff_wprep(const int* __restrict__ bsum, int* __restrict__ boff,
                                                     int nb, int* __restrict__ prow, int N,
                                                     const float* __restrict__ W2, const float* __restrict__ Wlin,
                                                     unsigned* __restrict__ wswz) {
    int t = threadIdx.x;
    if (blockIdx.x == 0) {
        __shared__ int s[1024];
        s[t] = (t < nb) ? bsum[t] : 0;
        __syncthreads();
        for (int off = 1; off < 1024; off <<= 1) {
            int v = (t >= off) ? s[t - off] : 0;
            __syncthreads();
            s[t] += v;
            __syncthreads();
        }
        if (t < nb) boff[t] = (t == 0) ? 0 : s[t - 1];
        if (t == 0) prow[N] = s[1023];
    } else {
        int tid = (blockIdx.x - 1) * 1024 + t;       // 0..24575 = 3*8192
        int m = tid >> 13;
        int r = tid & 8191;
        int jp = r & 3;
        int lane = (r >> 2) & 63;
        int ct = (r >> 8) & 7;
        int kc = r >> 11;
        int k0 = kc * 32 + (lane >> 4) * 8 + 2 * jp;
        int n = ct * 16 + (lane & 15);
        const float* srcp = (m == 0) ? W2 : (Wlin + (m - 1) * 16384);
        wswz[tid] = f2bf_pk(srcp[k0 * 128 + n], srcp[(k0 + 1) * 128 + n]);
    }
}

__global__ __launch_bounds__(256) void k_scan_final(const int* __restrict__ degi, const int* __restrict__ boff,
                                                    int* __restrict__ prow, int N) {
    __shared__ int s[256];
    int t = threadIdx.x;
    int i = blockIdx.x * 256 + t;
    int pd = (i < N) ? padded4(degi[i]) : 0;
    s[t] = pd;
    __syncthreads();
    for (int off = 1; off < 256; off <<= 1) {
        int v = (t >= off) ? s[t - off] : 0;
        __syncthreads();
        s[t] += v;
        __syncthreads();
    }
    if (i < N) prow[i] = boff[blockIdx.x] + ((t == 0) ? 0 : s[t - 1]);
}

// ---- Merged dispatch: scatter (int4, same copy map as k_degree8) | pad fill | xform1 ----
// blocks [0, eb4)           : scatter edges into padded CSR
// blocks [eb4, eb4+nb)      : fill pad slots with {N,0}; block eb4 also fills tail sentinels
// blocks [eb4+nb, ...+xb)   : g1 = bf16(dinv * (x @ W1)) (+ zero sentinel row)

__global__ __launch_bounds__(256) void k_scatter_fill_xform(
        const int* __restrict__ src, const int* __restrict__ dst, int E,
        const int* __restrict__ prow, int* __restrict__ hist8, const int* __restrict__ degi,
        int2* __restrict__ coleid, int N, int eb4, int nb,
        const float* __restrict__ x, const float* __restrict__ W1,
        const float* __restrict__ dinv, unsigned* __restrict__ g) {
    __shared__ float Ws[8 * D];
    int t = threadIdx.x;
    int b = blockIdx.x;
    if (b < eb4) {
        int i = b * 256 + t;
        int copy = b & 7;
        int E4 = E >> 2;
        if (i < E4) {
            int4 d = ((const int4*)dst)[i];
            int4 s4 = ((const int4*)src)[i];
            int* h = hist8 + copy * N;
            int e = i * 4;
            int off;
            off = atomicAdd(&h[d.x], 1); coleid[prow[d.x] + off] = make_int2(s4.x, e + 0);
            off = atomicAdd(&h[d.y], 1); coleid[prow[d.y] + off] = make_int2(s4.y, e + 1);
            off = atomicAdd(&h[d.z], 1); coleid[prow[d.z] + off] = make_int2(s4.z, e + 2);
            off = atomicAdd(&h[d.w], 1); coleid[prow[d.w] + off] = make_int2(s4.w, e + 3);
        }
        if (i == 0) {
            for (int j = E4 * 4; j < E; ++j) {
                int d = dst[j];
                int off = atomicAdd(&hist8[d], 1);   // copy 0
                coleid[prow[d] + off] = make_int2(src[j], j);
            }
        }
    } else if (b < eb4 + nb) {
        int n = (b - eb4) * 256 + t;
        if (n < N) {
            int lo = prow[n];
            int deg = degi[n];
            int pd = padded4(deg);
            for (int j = deg; j < pd; ++j) coleid[lo + j] = make_int2(N, 0);
        }
        if (b == eb4 && t == 0) {
            int P = prow[N];
            for (int j = 0; j < 16; ++j) coleid[P + j] = make_int2(N, 0);
        }
    } else {
        int xb0 = b - eb4 - nb;
        for (int i = t; i < 8 * D; i += 256) Ws[i] = W1[i];
        __syncthreads();
        int node = xb0 * 4 + (t >> 6);
        int l = t & 63;
        if (node < N) {
            float s0 = 0.f, s1 = 0.f;
#pragma unroll
            for (int k = 0; k < 8; ++k) {
                float xv = x[node * 8 + k];
                s0 += xv * Ws[k * D + 2 * l];
                s1 += xv * Ws[k * D + 2 * l + 1];
            }
            float di = dinv[node];
            g[node * 64 + l] = f2bf_pk(s0 * di, s1 * di);
        }
        if (xb0 == 0 && t < 64) g[(size_t)N * 64 + t] = 0;   // zero sentinel row
    }
}

// ---- Fused aggregation + MFMA GEMM ----
// Block = 4 waves, 16-node tile. Each wave aggregates 4 nodes (CSR gather, packed f32x2 math),
// stages h rows (bf16) in LDS; then each wave MFMAs the tile against 2 column-tiles of W.
// DUAL=false: out0 = bf16(dinv * (h@W0))            (layer-2 g2)
// DUAL=true : out0 = bf16(h@W0) ; out1 = bf16(h@W1 + bias1)   (edge-MLP a,c)

#define HROW 136   // u16 per LDS row (128 + 8 pad -> 272 B row stride)

template <bool DUAL>
__global__ __launch_bounds__(256) void k_aggemm(const uint4* __restrict__ g, const int* __restrict__ prow,
                                                const int2* __restrict__ coleid, const float* __restrict__ dinv,
                                                const float* __restrict__ biasH,
                                                const uint4* __restrict__ wB0, const uint4* __restrict__ wB1,
                                                const float* __restrict__ bias1,
                                                u16* __restrict__ out0, u16* __restrict__ out1, int N) {
    __shared__ u16 hs[16 * HROW];
    int t = threadIdx.x;
    int wv = t >> 6;
    int lane = t & 63;
    int sub = lane >> 4;
    int r = lane & 15;
    int base = blockIdx.x * 16;

    // ---- aggregation phase: 4 nodes per wave ----
    for (int nd = 0; nd < 4; ++nd) {
        int i = base + wv * 4 + nd;
        int lrow = wv * 4 + nd;
        if (i < N) {
            f32x2 acc2[4];
#pragma unroll
            for (int j = 0; j < 4; ++j) acc2[j] = (f32x2)(0.f);
            int lo = prow[i], hiP = prow[i + 1];
            int idx = lo + sub;
            int c0 = coleid[idx].x;
            int c1 = (idx + 4 < hiP) ? coleid[idx + 4].x : N;
            int c2 = (idx + 8 < hiP) ? coleid[idx + 8].x : N;
            uint4 v0 = g[c0 * 16 + r];
            uint4 v1 = g[c1 * 16 + r];
            for (int k = lo; k < hiP; k += 4) {
                int c3 = (idx + 12 < hiP) ? coleid[idx + 12].x : N;
                uint4 v2 = g[c2 * 16 + r];
                acc2[0] += bf2f2v(v0.x);
                acc2[1] += bf2f2v(v0.y);
                acc2[2] += bf2f2v(v0.z);
                acc2[3] += bf2f2v(v0.w);
                v0 = v1; v1 = v2; c2 = c3; idx += 4;
            }
#pragma unroll
            for (int j = 0; j < 4; ++j) {
                acc2[j].x += __shfl_xor(acc2[j].x, 16, 64);
                acc2[j].y += __shfl_xor(acc2[j].y, 16, 64);
                acc2[j].x += __shfl_xor(acc2[j].x, 32, 64);
                acc2[j].y += __shfl_xor(acc2[j].y, 32, 64);
            }
            if (sub == 0) {
                uint4 sv = g[i * 16 + r];   // self term
                acc2[0] += bf2f2v(sv.x);
                acc2[1] += bf2f2v(sv.y);
                acc2[2] += bf2f2v(sv.z);
                acc2[3] += bf2f2v(sv.w);
                float di = dinv[i];
                float4 b0 = ((const float4*)biasH)[r * 2];
                float4 b1v = ((const float4*)biasH)[r * 2 + 1];
                float r0 = fmaxf(acc2[0].x * di + b0.x, 0.f);
                float r1 = fmaxf(acc2[0].y * di + b0.y, 0.f);
                float r2 = fmaxf(acc2[1].x * di + b0.z, 0.f);
                float r3 = fmaxf(acc2[1].y * di + b0.w, 0.f);
                float r4 = fmaxf(acc2[2].x * di + b1v.x, 0.f);
                float r5 = fmaxf(acc2[2].y * di + b1v.y, 0.f);
                float r6 = fmaxf(acc2[3].x * di + b1v.z, 0.f);
                float r7 = fmaxf(acc2[3].y * di + b1v.w, 0.f);
                uint4 o;
                o.x = f2bf_pk(r0, r1);
                o.y = f2bf_pk(r2, r3);
                o.z = f2bf_pk(r4, r5);
                o.w = f2bf_pk(r6, r7);
                *(uint4*)(hs + lrow * HROW + r * 8) = o;
            }
        } else if (sub == 0) {
            *(uint4*)(hs + lrow * HROW + r * 8) = make_uint4(0, 0, 0, 0);
        }
    }
    __syncthreads();

    // ---- GEMM phase: wave wv handles column-tiles ct0, ct0+1 ----
    int quad = lane >> 4;
    int l15 = lane & 15;
    int ct0 = wv * 2;

    f32x4 accA[2], accB[2];
#pragma unroll
    for (int q = 0; q < 2; ++q) { accA[q] = (f32x4){0.f, 0.f, 0.f, 0.f}; accB[q] = (f32x4){0.f, 0.f, 0.f, 0.f}; }

    const uint4* hrow = (const uint4*)(hs + l15 * HROW);
#pragma unroll
    for (int kc = 0; kc < 4; ++kc) {
        BU a; a.u = hrow[kc * 4 + quad];
#pragma unroll
        for (int q = 0; q < 2; ++q) {
            BU b0; b0.u = wB0[(kc * 8 + ct0 + q) * 64 + lane];
            accA[q] = __builtin_amdgcn_mfma_f32_16x16x32_bf16(a.s, b0.s, accA[q], 0, 0, 0);
            if (DUAL) {
                BU b1; b1.u = wB1[(kc * 8 + ct0 + q) * 64 + lane];
                accB[q] = __builtin_amdgcn_mfma_f32_16x16x32_bf16(a.s, b1.s, accB[q], 0, 0, 0);
            }
        }
    }
#pragma unroll
    for (int reg = 0; reg < 4; ++reg) {
        int node = base + quad * 4 + reg;
        if (node >= N) continue;
        float sc = DUAL ? 1.0f : dinv[node];
#pragma unroll
        for (int q = 0; q < 2; ++q) {
            int colj = (ct0 + q) * 16 + l15;
            out0[(size_t)node * 128 + colj] = f2bf(accA[q][reg] * sc);
            if (DUAL) out1[(size_t)node * 128 + colj] = f2bf(accB[q][reg] + bias1[colj]);
        }
    }
    if (blockIdx.x == 0 && t < 64) ((unsigned*)out0)[(size_t)N * 64 + t] = 0;   // zero sentinel row
}

// ---- Edge output: padded CSR, depth-2 pipeline, packed f32x2 math ----

__global__ __launch_bounds__(256) void k_edge(const uint4* __restrict__ a, const uint4* __restrict__ c,
                                              const int* __restrict__ prow, const int* __restrict__ degi,
                                              const int2* __restrict__ coleid,
                                              const float* __restrict__ Wfin, const float* __restrict__ bfin,
                                              float* __restrict__ out, int N) {
    int wave = (blockIdx.x * blockDim.x + threadIdx.x) >> 6;
    int lane = threadIdx.x & 63;
    if (wave >= N) return;
    int d = wave;
    int g = lane >> 4;
    int r = lane & 15;

    f32x2 wf0v[4], wf1v[4];
    const float4* wvp = (const float4*)Wfin;
#pragma unroll
    for (int q = 0; q < 4; ++q) {
        float4 m = wvp[r * 4 + q];
        wf0v[q] = (f32x2){m.x, m.z};
        wf1v[q] = (f32x2){m.y, m.w};
    }
    float bf0 = bfin[0], bf1 = bfin[1];

    f32x2 cf2[4];
    {
        uint4 cv = c[d * 16 + r];
        cf2[0] = bf2f2v(cv.x);
        cf2[1] = bf2f2v(cv.y);
        cf2[2] = bf2f2v(cv.z);
        cf2[3] = bf2f2v(cv.w);
    }

    int lo = prow[d], hiP = prow[d + 1];
    int deg = degi[d];

    int idx = lo + g;
    int2 q0 = coleid[idx];
    int2 q1 = coleid[idx + 4];
    int c1 = (idx + 4 < hiP) ? q1.x : N;
    int2 q2 = coleid[idx + 8];
    int c2 = (idx + 8 < hiP) ? q2.x : N;
    int e0 = q0.y, e1 = q1.y, e2 = q2.y;
    uint4 v0 = a[q0.x * 16 + r];
    uint4 v1 = a[c1 * 16 + r];

    int rel = g;
    for (int k = lo; k < hiP; k += 4) {
        int2 q3 = coleid[idx + 12];
        int c3 = (idx + 12 < hiP) ? q3.x : N;
        uint4 v2 = a[c2 * 16 + r];
        f32x2 p0v = (f32x2)(0.f), p1v = (f32x2)(0.f);
        f32x2 z;
        z = vmax0(bf2f2v(v0.x) + cf2[0]); p0v += z * wf0v[0]; p1v += z * wf1v[0];
        z = vmax0(bf2f2v(v0.y) + cf2[1]); p0v += z * wf0v[1]; p1v += z * wf1v[1];
        z = vmax0(bf2f2v(v0.z) + cf2[2]); p0v += z * wf0v[2]; p1v += z * wf1v[2];
        z = vmax0(bf2f2v(v0.w) + cf2[3]); p0v += z * wf0v[3]; p1v += z * wf1v[3];
        float p0 = p0v.x + p0v.y;
        float p1 = p1v.x + p1v.y;
        p0 += __shfl_xor(p0, 1, 64);
        p0 += __shfl_xor(p0, 2, 64);
        p0 += __shfl_xor(p0, 4, 64);
        p0 += __shfl_xor(p0, 8, 64);
        p1 += __shfl_xor(p1, 1, 64);
        p1 += __shfl_xor(p1, 2, 64);
        p1 += __shfl_xor(p1, 4, 64);
        p1 += __shfl_xor(p1, 8, 64);
        if (r == 0 && rel < deg) {
            float l0 = p0 + bf0, l1 = p1 + bf1;
            float m = fmaxf(l0, l1);
            float lse = m + __logf(__expf(l0 - m) + __expf(l1 - m));
            *((float2*)(out + 2 * (size_t)e0)) = make_float2(l0 - lse, l1 - lse);
        }
        v0 = v1; v1 = v2;
        e0 = e1; e1 = e2; e2 = q3.y;
        c2 = c3; idx += 4; rel += 4;
    }
}

extern "C" void kernel_launch(void* const* d_in, const int* in_sizes, int n_in,
                              void* d_out, int out_size, void* d_ws, size_t ws_size,
                              hipStream_t stream) {
    const float* x     = (const float*)d_in[0];
    const int*   ei    = (const int*)d_in[1];
    const float* W1    = (const float*)d_in[2];
    const float* b1    = (const float*)d_in[3];
    const float* W2    = (const float*)d_in[4];
    const float* b2    = (const float*)d_in[5];
    const float* Wlin1 = (const float*)d_in[6];
    const float* blin1 = (const float*)d_in[7];
    const float* Wfin  = (const float*)d_in[8];
    const float* bfin  = (const float*)d_in[9];
    float* out = (float*)d_out;

    int N = in_sizes[0] / 8;
    int E = in_sizes[1] / 2;
    const int* src = ei;
    const int* dst = ei + E;
    int nb = (N + 255) / 256;
    int eb4 = (E / 4 + 255) / 256;
    int xb = (N + 3) / 4;

    char* w = (char*)d_ws;
    int* hist8 = (int*)w;     w += (size_t)8 * N * 4;
    int* degi = (int*)w;      w += (size_t)N * 4;
    int* prow = (int*)w;      w += (size_t)(N + 1) * 4;
    float* dinv = (float*)w;  w += (size_t)N * 4;
    int* bsum = (int*)w;      w += (size_t)nb * 4;
    int* boff = (int*)w;      w += (size_t)nb * 4;
    w = (char*)(((uintptr_t)w + 255) & ~(uintptr_t)255);
    int2* coleid = (int2*)w;  w += ((size_t)E + 8 * (size_t)N + 64) * 8;
    unsigned* wswz = (unsigned*)w; w += (size_t)3 * 8192 * 4;
    unsigned* bufG = (unsigned*)w; w += (size_t)(N + 1) * 64 * 4;   // g1 + sentinel
    unsigned* bufA = (unsigned*)w; w += (size_t)(N + 1) * 64 * 4;   // a + sentinel
    unsigned* bufC = (unsigned*)w; w += (size_t)N * 64 * 4;         // c
    unsigned* bufG2 = (unsigned*)w; w += (size_t)(N + 1) * 64 * 4;  // g2 + sentinel

    hipMemsetAsync(hist8, 0, (size_t)8 * N * 4, stream);

    k_degree8<<<eb4, 256, 0, stream>>>(dst, E, hist8, N);
    k_xcdoff_bsum<<<nb, 256, 0, stream>>>(hist8, degi, dinv, bsum, N);
    k_boff_wprep<<<25, 1024, 0, stream>>>(bsum, boff, nb, prow, N, W2, Wlin1, wswz);
    k_scan_final<<<nb, 256, 0, stream>>>(degi, boff, prow, N);
    // merged: scatter | pad fill | layer-1 transform (independent work, one dispatch)
    k_scatter_fill_xform<<<eb4 + nb + xb, 256, 0, stream>>>(src, dst, E, prow, hist8, degi,
                                                            coleid, N, eb4, nb, x, W1, dinv, bufG);

    int ablocks = (N + 15) / 16;
    // fused: agg(g1)->h1 -> GEMM W2 -> g2 (dinv-scaled) + sentinel
    k_aggemm<false><<<ablocks, 256, 0, stream>>>((const uint4*)bufG, prow, coleid, dinv, b1,
                                                 (const uint4*)wswz, nullptr, nullptr,
                                                 (u16*)bufG2, nullptr, N);
    // fused: agg(g2)->h2 -> dual GEMM -> a (+sentinel), c (+blin1)
    k_aggemm<true><<<ablocks, 256, 0, stream>>>((const uint4*)bufG2, prow, coleid, dinv, b2,
                                                (const uint4*)(wswz + 8192), (const uint4*)(wswz + 16384),
                                                blin1, (u16*)bufA, (u16*)bufC, N);

    k_edge<<<(N + 3) / 4, 256, 0, stream>>>((const uint4*)bufA, (const uint4*)bufC,
                                            prow, degi, coleid, Wfin, bfin, out, N);
}